// Round 1
// baseline (793.259 us; speedup 1.0000x reference)
//
#include <hip/hip_runtime.h>
#include <stdint.h>

#define NN 100000   // nodes
#define NREL 3
#define NE 200000   // edges per relation
#define F 128       // feature dim (in = hid = out)
#define NQ 4096

typedef float fx4 __attribute__((ext_vector_type(4)));
typedef unsigned short u16x8 __attribute__((ext_vector_type(8)));
typedef __bf16 bf16x8 __attribute__((ext_vector_type(8)));

__device__ __forceinline__ unsigned short f2bf(float f) {
  uint32_t u = __builtin_bit_cast(uint32_t, f);
  uint32_t r = u + 0x7FFFu + ((u >> 16) & 1u);
  return (unsigned short)(r >> 16);
}

// ---- degree accumulation (both layers share degrees) ----
__global__ void deg_kernel(const int* __restrict__ es, const int* __restrict__ ed,
                           float* __restrict__ deg_out, float* __restrict__ deg_in) {
  int i = blockIdx.x * blockDim.x + threadIdx.x;
  if (i >= NREL * NE) return;
  int r = i / NE;
  atomicAdd(&deg_out[r * NN + es[i]], 1.0f);
  atomicAdd(&deg_in[r * NN + ed[i]], 1.0f);
}

__global__ void rsqrt_kernel(float* __restrict__ d) {
  int i = blockIdx.x * blockDim.x + threadIdx.x;
  if (i >= 2 * NREL * NN) return;
  d[i] = rsqrtf(fmaxf(d[i], 1.0f));
}

// Wtb[layer][rel][n][k] = bf16(W[layer][rel][k][n])  (transposed for contiguous-k frag reads)
__global__ void wcvt_kernel(const float* __restrict__ W1, const float* __restrict__ W2,
                            unsigned short* __restrict__ Wtb) {
  int i = blockIdx.x * blockDim.x + threadIdx.x;
  if (i >= 2 * NREL * F * F) return;
  int l = i / (NREL * F * F);
  int rem = i % (NREL * F * F);
  int r = rem / (F * F);
  int nk = rem % (F * F);
  int n = nk >> 7, k = nk & 127;
  const float* W = l ? W2 : W1;
  Wtb[i] = f2bf(W[r * F * F + k * F + n]);
}

// X (f32) -> Xb (bf16), unscaled (degree scaling folded into scatter)
__global__ void cvtx_kernel(const float* __restrict__ x, unsigned short* __restrict__ xb) {
  int i = blockIdx.x * blockDim.x + threadIdx.x;  // one per 8 elems
  const float* p = x + (size_t)i * 8;
  unsigned short tmp[8];
#pragma unroll
  for (int e = 0; e < 8; ++e) tmp[e] = f2bf(p[e]);
  *reinterpret_cast<u16x8*>(xb + (size_t)i * 8) = *reinterpret_cast<u16x8*>(tmp);
}

// y[M,128] = Xb[M,128] @ W[128,128] via mfma_f32_16x16x32_bf16
// block: 256 thr (4 waves), M-tile 64 (wave w -> rows w*16..w*16+15), full N=128
#define BM 64
#define LDP 136  // padded lds row stride (elems): +8 -> only free 2-way conflicts
__global__ __launch_bounds__(256) void gemm_kernel(const unsigned short* __restrict__ Xb,
                                                   const unsigned short* __restrict__ Wt,
                                                   float* __restrict__ y, int nrows) {
  __shared__ unsigned short A_lds[BM * LDP];
  __shared__ unsigned short W_lds[F * LDP];
  const int t = threadIdx.x;
  const int m0 = blockIdx.x * BM;

  // stage Wt (bf16, [n][k]) -> LDS: 2048 chunks of 8
#pragma unroll
  for (int i = 0; i < 8; ++i) {
    int c = t + i * 256;
    int n = c >> 4, kc = (c & 15) * 8;
    *reinterpret_cast<u16x8*>(&W_lds[n * LDP + kc]) =
        *reinterpret_cast<const u16x8*>(Wt + n * F + kc);
  }
  // stage A tile: 1024 chunks of 8
#pragma unroll
  for (int i = 0; i < 4; ++i) {
    int c = t + i * 256;
    int row = c >> 4, cg = (c & 15) * 8;
    int gm = m0 + row;
    u16x8 v;
    if (gm < nrows) {
      v = *reinterpret_cast<const u16x8*>(Xb + (size_t)gm * F + cg);
    } else {
      v = (u16x8)0;
    }
    *reinterpret_cast<u16x8*>(&A_lds[row * LDP + cg]) = v;
  }
  __syncthreads();

  const int lane = t & 63, w = t >> 6;
  const int r0 = lane & 15, kq = lane >> 4;
  fx4 acc[8];
#pragma unroll
  for (int nt = 0; nt < 8; ++nt) acc[nt] = (fx4){0.f, 0.f, 0.f, 0.f};

  const unsigned short* ap = &A_lds[(w * 16 + r0) * LDP + kq * 8];
  const unsigned short* bp = &W_lds[r0 * LDP + kq * 8];
#pragma unroll
  for (int kb = 0; kb < 4; ++kb) {
    bf16x8 a = __builtin_bit_cast(bf16x8, *reinterpret_cast<const u16x8*>(ap + kb * 32));
#pragma unroll
    for (int nt = 0; nt < 8; ++nt) {
      bf16x8 b = __builtin_bit_cast(bf16x8,
          *reinterpret_cast<const u16x8*>(bp + nt * 16 * LDP + kb * 32));
      acc[nt] = __builtin_amdgcn_mfma_f32_16x16x32_bf16(a, b, acc[nt], 0, 0, 0);
    }
  }
  // C/D layout: col = lane&15, row = (lane>>4)*4 + reg  [m89-verified]
  const int rbase = m0 + w * 16 + kq * 4;
#pragma unroll
  for (int nt = 0; nt < 8; ++nt) {
    int col = nt * 16 + r0;
#pragma unroll
    for (int reg = 0; reg < 4; ++reg) {
      int gm = rbase + reg;
      if (gm < nrows) y[(size_t)gm * F + col] = acc[nt][reg];
    }
  }
}

// acc[dst] += y[src] * rs_out[src] * rs_in[dst]   (128 thr per edge, 2 edges/block)
__global__ __launch_bounds__(256) void scatter_kernel(const float* __restrict__ y,
                                                      const int* __restrict__ es,
                                                      const int* __restrict__ ed,
                                                      const float* __restrict__ rs_out,
                                                      const float* __restrict__ rs_in,
                                                      float* __restrict__ acc) {
  int t = threadIdx.x;
  int e = blockIdx.x * 2 + (t >> 7);
  int f = t & 127;
  int s = es[e], d = ed[e];
  float v = y[(size_t)s * F + f] * rs_out[s] * rs_in[d];
  atomicAdd(&acc[(size_t)d * F + f], v);
}

// out = tanh(acc + sum_r b[r])
__global__ void bias_tanh_kernel(const float* __restrict__ acc, const float* __restrict__ b,
                                 float* __restrict__ out) {
  int i = blockIdx.x * blockDim.x + threadIdx.x;
  if (i >= NN * F) return;
  int f = i & 127;
  float bb = b[f] + b[F + f] + b[2 * F + f];
  out[i] = tanhf(acc[i] + bb);
}

__global__ void gather_kernel(const float* __restrict__ h, const int* __restrict__ qsrc,
                              const int* __restrict__ qdst, float* __restrict__ out) {
  int i = blockIdx.x * blockDim.x + threadIdx.x;  // 2*NQ*F total
  int q = i >> 7, f = i & 127;
  int node = (q < NQ) ? qsrc[q] : qdst[q - NQ];
  out[i] = h[(size_t)node * F + f];
}

extern "C" void kernel_launch(void* const* d_in, const int* in_sizes, int n_in,
                              void* d_out, int out_size, void* d_ws, size_t ws_size,
                              hipStream_t stream) {
  const float* emb = (const float*)d_in[0];
  const float* W1  = (const float*)d_in[1];
  const float* b1  = (const float*)d_in[2];
  const float* W2  = (const float*)d_in[3];
  const float* b2  = (const float*)d_in[4];
  const int* e_src = (const int*)d_in[5];
  const int* e_dst = (const int*)d_in[6];
  const int* qsrc  = (const int*)d_in[7];
  const int* qdst  = (const int*)d_in[8];
  float* out = (float*)d_out;

  char* p = (char*)d_ws;
  size_t off = 0;
  auto take = [&](size_t n) { void* q = p + off; off = (off + n + 255) & ~(size_t)255; return q; };
  float* rs           = (float*)take(2ull * NREL * NN * 4);      // deg -> rsqrt, [out|in][3][NN]
  unsigned short* Wtb = (unsigned short*)take(2ull * NREL * F * F * 2);
  unsigned short* Xb  = (unsigned short*)take((size_t)NN * F * 2);
  float* y   = (float*)take((size_t)NN * F * 4);
  float* acc = (float*)take((size_t)NN * F * 4);
  float* h   = (float*)take((size_t)NN * F * 4);

  float* rs_out = rs;
  float* rs_in  = rs + (size_t)NREL * NN;

  hipMemsetAsync(rs, 0, 2ull * NREL * NN * 4, stream);
  deg_kernel<<<(NREL * NE + 255) / 256, 256, 0, stream>>>(e_src, e_dst, rs_out, rs_in);
  rsqrt_kernel<<<(2 * NREL * NN + 255) / 256, 256, 0, stream>>>(rs);
  wcvt_kernel<<<(2 * NREL * F * F + 255) / 256, 256, 0, stream>>>(W1, W2, Wtb);

  const int gemm_grid = (NN + BM - 1) / BM;
  for (int layer = 0; layer < 2; ++layer) {
    const float* xin = layer ? h : emb;
    cvtx_kernel<<<(NN * F / 8 + 255) / 256, 256, 0, stream>>>(xin, Xb);
    hipMemsetAsync(acc, 0, (size_t)NN * F * 4, stream);
    for (int r = 0; r < NREL; ++r) {
      gemm_kernel<<<gemm_grid, 256, 0, stream>>>(
          Xb, Wtb + (size_t)(layer * NREL + r) * F * F, y, NN);
      scatter_kernel<<<NE / 2, 256, 0, stream>>>(
          y, e_src + (size_t)r * NE, e_dst + (size_t)r * NE,
          rs_out + (size_t)r * NN, rs_in + (size_t)r * NN, acc);
    }
    const float* bb = layer ? b2 : b1;
    float* hout = layer ? acc : h;  // layer2 tanh in place; gather reads acc
    bias_tanh_kernel<<<(NN * F + 255) / 256, 256, 0, stream>>>(acc, bb, hout);
  }
  gather_kernel<<<(2 * NQ * F) / 256, 256, 0, stream>>>(acc, qsrc, qdst, out);
}

// Round 2
// 627.821 us; speedup vs baseline: 1.2635x; 1.2635x over previous
//
#include <hip/hip_runtime.h>
#include <stdint.h>

#define NN 100000   // nodes
#define NREL 3
#define NE 200000   // edges per relation
#define F 128       // feature dim (in = hid = out)
#define NQ 4096

typedef float fx4 __attribute__((ext_vector_type(4)));
typedef unsigned short u16x8 __attribute__((ext_vector_type(8)));
typedef __bf16 bf16x8 __attribute__((ext_vector_type(8)));

__device__ __forceinline__ unsigned short f2bf(float f) {
  uint32_t u = __builtin_bit_cast(uint32_t, f);
  uint32_t r = u + 0x7FFFu + ((u >> 16) & 1u);
  return (unsigned short)(r >> 16);
}
__device__ __forceinline__ float bf2f(unsigned short u) {
  return __builtin_bit_cast(float, (uint32_t)u << 16);
}

// ---- integer degree counts: cnt[0..3NN) = out-deg per rel, cnt[3NN..6NN) = in-deg ----
__global__ void cnt_kernel(const int* __restrict__ es, const int* __restrict__ ed,
                           int* __restrict__ cnt) {
  int i = blockIdx.x * blockDim.x + threadIdx.x;
  if (i >= NREL * NE) return;
  int r = i / NE;
  atomicAdd(&cnt[r * NN + es[i]], 1);
  atomicAdd(&cnt[NREL * NN + r * NN + ed[i]], 1);
}

// rs[i] = rsqrt(max(cnt[i],1)) for both out and in halves
__global__ void rs_kernel(const int* __restrict__ cnt, float* __restrict__ rs) {
  int i = blockIdx.x * blockDim.x + threadIdx.x;
  if (i >= 2 * NREL * NN) return;
  rs[i] = rsqrtf((float)max(cnt[i], 1));
}

// per (rel,node) dst-bucket: claim contiguous region; zero fill cursor
__global__ void bucket_kernel(const int* __restrict__ cnt_in, int* __restrict__ start,
                              int* __restrict__ fill, int* __restrict__ cursor) {
  int i = blockIdx.x * blockDim.x + threadIdx.x;
  if (i >= NREL * NN) return;
  start[i] = atomicAdd(cursor, cnt_in[i]);
  fill[i] = 0;
}

// place each edge's (rel*NN + src) into its dst bucket
__global__ void fill_kernel(const int* __restrict__ es, const int* __restrict__ ed,
                            const int* __restrict__ start, int* __restrict__ fill,
                            int* __restrict__ epay) {
  int i = blockIdx.x * blockDim.x + threadIdx.x;
  if (i >= NREL * NE) return;
  int r = i / NE;
  int b = r * NN + ed[i];
  int pos = start[b] + atomicAdd(&fill[b], 1);
  epay[pos] = r * NN + es[i];
}

// Wtb[layer][rel][n][k] = bf16(W[layer][rel][k][n])
__global__ void wcvt_kernel(const float* __restrict__ W1, const float* __restrict__ W2,
                            unsigned short* __restrict__ Wtb) {
  int i = blockIdx.x * blockDim.x + threadIdx.x;
  if (i >= 2 * NREL * F * F) return;
  int l = i / (NREL * F * F);
  int rem = i % (NREL * F * F);
  int r = rem / (F * F);
  int nk = rem % (F * F);
  int n = nk >> 7, k = nk & 127;
  const float* W = l ? W2 : W1;
  Wtb[i] = f2bf(W[r * F * F + k * F + n]);
}

// X (f32) -> Xb (bf16)
__global__ void cvtx_kernel(const float* __restrict__ x, unsigned short* __restrict__ xb) {
  int i = blockIdx.x * blockDim.x + threadIdx.x;  // one per 8 elems
  const float* p = x + (size_t)i * 8;
  unsigned short tmp[8];
#pragma unroll
  for (int e = 0; e < 8; ++e) tmp[e] = f2bf(p[e]);
  *reinterpret_cast<u16x8*>(xb + (size_t)i * 8) = *reinterpret_cast<u16x8*>(tmp);
}

// y[M,128] = bf16( rs_out[m] * (Xb[M,128] @ W[128,128]) ) via mfma_f32_16x16x32_bf16
#define BM 64
#define LDP 136
__global__ __launch_bounds__(256) void gemm_kernel(const unsigned short* __restrict__ Xb,
                                                   const unsigned short* __restrict__ Wt,
                                                   const float* __restrict__ rs_out,
                                                   unsigned short* __restrict__ y, int nrows) {
  __shared__ unsigned short A_lds[BM * LDP];
  __shared__ unsigned short W_lds[F * LDP];
  const int t = threadIdx.x;
  const int m0 = blockIdx.x * BM;

#pragma unroll
  for (int i = 0; i < 8; ++i) {
    int c = t + i * 256;
    int n = c >> 4, kc = (c & 15) * 8;
    *reinterpret_cast<u16x8*>(&W_lds[n * LDP + kc]) =
        *reinterpret_cast<const u16x8*>(Wt + n * F + kc);
  }
#pragma unroll
  for (int i = 0; i < 4; ++i) {
    int c = t + i * 256;
    int row = c >> 4, cg = (c & 15) * 8;
    int gm = m0 + row;
    u16x8 v;
    if (gm < nrows) {
      v = *reinterpret_cast<const u16x8*>(Xb + (size_t)gm * F + cg);
    } else {
      v = (u16x8)0;
    }
    *reinterpret_cast<u16x8*>(&A_lds[row * LDP + cg]) = v;
  }
  __syncthreads();

  const int lane = t & 63, w = t >> 6;
  const int r0 = lane & 15, kq = lane >> 4;
  fx4 acc[8];
#pragma unroll
  for (int nt = 0; nt < 8; ++nt) acc[nt] = (fx4){0.f, 0.f, 0.f, 0.f};

  const unsigned short* ap = &A_lds[(w * 16 + r0) * LDP + kq * 8];
  const unsigned short* bp = &W_lds[r0 * LDP + kq * 8];
#pragma unroll
  for (int kb = 0; kb < 4; ++kb) {
    bf16x8 a = __builtin_bit_cast(bf16x8, *reinterpret_cast<const u16x8*>(ap + kb * 32));
#pragma unroll
    for (int nt = 0; nt < 8; ++nt) {
      bf16x8 b = __builtin_bit_cast(bf16x8,
          *reinterpret_cast<const u16x8*>(bp + nt * 16 * LDP + kb * 32));
      acc[nt] = __builtin_amdgcn_mfma_f32_16x16x32_bf16(a, b, acc[nt], 0, 0, 0);
    }
  }
  // C/D layout: col = lane&15, row = (lane>>4)*4 + reg
  const int rbase = m0 + w * 16 + kq * 4;
  float sc[4];
#pragma unroll
  for (int reg = 0; reg < 4; ++reg)
    sc[reg] = (rbase + reg < nrows) ? rs_out[rbase + reg] : 0.f;
#pragma unroll
  for (int nt = 0; nt < 8; ++nt) {
    int col = nt * 16 + r0;
#pragma unroll
    for (int reg = 0; reg < 4; ++reg) {
      int gm = rbase + reg;
      if (gm < nrows) y[(size_t)gm * F + col] = f2bf(acc[nt][reg] * sc[reg]);
    }
  }
}

// fused aggregate: h[n] = tanh( sum_r rs_in_r[n] * sum_{e in bucket(r,n)} y[pay_e] + sum_r b_r )
// 2 nodes per 256-thread block, 128 threads (= 2 waves) per node.
__global__ __launch_bounds__(256) void agg_kernel(const unsigned short* __restrict__ ybuf,
                                                  const int* __restrict__ start,
                                                  const int* __restrict__ cnt_in,
                                                  const int* __restrict__ epay,
                                                  const float* __restrict__ rs_in,
                                                  const float* __restrict__ b,
                                                  float* __restrict__ hout,
                                                  unsigned short* __restrict__ xbout) {
  int t = threadIdx.x;
  int n = blockIdx.x * 2 + (t >> 7);
  int f = t & 127;
  float acc = 0.f;
#pragma unroll
  for (int r = 0; r < NREL; ++r) {
    int base = r * NN + n;
    int s0 = start[base];
    int c = cnt_in[base];
    float sum = 0.f;
    for (int i = 0; i < c; ++i) {
      int p = epay[s0 + i];
      sum += bf2f(ybuf[((size_t)p << 7) + f]);
    }
    acc += sum * rs_in[base];
  }
  float bb = b[f] + b[F + f] + b[2 * F + f];
  float v = tanhf(acc + bb);
  if (hout) hout[(size_t)n * F + f] = v;
  if (xbout) xbout[(size_t)n * F + f] = f2bf(v);
}

__global__ void gather_kernel(const float* __restrict__ h, const int* __restrict__ qsrc,
                              const int* __restrict__ qdst, float* __restrict__ out) {
  int i = blockIdx.x * blockDim.x + threadIdx.x;  // 2*NQ*F total
  int q = i >> 7, f = i & 127;
  int node = (q < NQ) ? qsrc[q] : qdst[q - NQ];
  out[i] = h[(size_t)node * F + f];
}

extern "C" void kernel_launch(void* const* d_in, const int* in_sizes, int n_in,
                              void* d_out, int out_size, void* d_ws, size_t ws_size,
                              hipStream_t stream) {
  const float* emb = (const float*)d_in[0];
  const float* W1  = (const float*)d_in[1];
  const float* b1  = (const float*)d_in[2];
  const float* W2  = (const float*)d_in[3];
  const float* b2  = (const float*)d_in[4];
  const int* e_src = (const int*)d_in[5];
  const int* e_dst = (const int*)d_in[6];
  const int* qsrc  = (const int*)d_in[7];
  const int* qdst  = (const int*)d_in[8];
  float* out = (float*)d_out;

  char* p = (char*)d_ws;
  size_t off = 0;
  auto take = [&](size_t n) { void* q = p + off; off = (off + n + 255) & ~(size_t)255; return q; };
  int* cnt    = (int*)take(2ull * NREL * NN * 4 + 4);   // [out|in] counts + cursor tail
  int* cursor = cnt + 2 * NREL * NN;
  float* rs   = (float*)take(2ull * NREL * NN * 4);     // rsqrt of [out|in]
  int* start  = (int*)take((size_t)NREL * NN * 4);
  int* fill   = (int*)take((size_t)NREL * NN * 4);
  int* epay   = (int*)take((size_t)NREL * NE * 4);
  unsigned short* Wtb = (unsigned short*)take(2ull * NREL * F * F * 2);
  unsigned short* Xb  = (unsigned short*)take((size_t)NN * F * 2);
  unsigned short* ybuf = (unsigned short*)take((size_t)NREL * NN * F * 2);
  float* h    = (float*)take((size_t)NN * F * 4);

  float* rs_out = rs;
  float* rs_in  = rs + (size_t)NREL * NN;
  int* cnt_in   = cnt + (size_t)NREL * NN;

  hipMemsetAsync(cnt, 0, 2ull * NREL * NN * 4 + 4, stream);
  cnt_kernel<<<(NREL * NE + 255) / 256, 256, 0, stream>>>(e_src, e_dst, cnt);
  rs_kernel<<<(2 * NREL * NN + 255) / 256, 256, 0, stream>>>(cnt, rs);
  bucket_kernel<<<(NREL * NN + 255) / 256, 256, 0, stream>>>(cnt_in, start, fill, cursor);
  fill_kernel<<<(NREL * NE + 255) / 256, 256, 0, stream>>>(e_src, e_dst, start, fill, epay);
  wcvt_kernel<<<(2 * NREL * F * F + 255) / 256, 256, 0, stream>>>(W1, W2, Wtb);
  cvtx_kernel<<<(NN * F / 8 + 255) / 256, 256, 0, stream>>>(emb, Xb);

  const int gemm_grid = (NN + BM - 1) / BM;
  for (int layer = 0; layer < 2; ++layer) {
    for (int r = 0; r < NREL; ++r) {
      gemm_kernel<<<gemm_grid, 256, 0, stream>>>(
          Xb, Wtb + (size_t)(layer * NREL + r) * F * F,
          rs_out + (size_t)r * NN,
          ybuf + (size_t)r * NN * F, NN);
    }
    const float* bb = layer ? b2 : b1;
    agg_kernel<<<NN / 2, 256, 0, stream>>>(
        ybuf, start, cnt_in, epay, rs_in, bb,
        layer ? h : nullptr,          // layer 2 writes f32 h for the final gather
        layer ? nullptr : Xb);        // layer 1 writes only bf16 Xb for the next GEMM
  }
  gather_kernel<<<(2 * NQ * F) / 256, 256, 0, stream>>>(h, qsrc, qdst, out);
}

// Round 3
// 404.410 us; speedup vs baseline: 1.9615x; 1.5524x over previous
//
#include <hip/hip_runtime.h>
#include <stdint.h>

#define NN 100000   // nodes
#define NREL 3
#define NE 200000   // edges per relation
#define F 128       // feature dim (in = hid = out)
#define NQ 4096

typedef float fx4 __attribute__((ext_vector_type(4)));
typedef unsigned short u16x8 __attribute__((ext_vector_type(8)));
typedef __bf16 bf16x8 __attribute__((ext_vector_type(8)));

__device__ __forceinline__ unsigned short f2bf(float f) {
  uint32_t u = __builtin_bit_cast(uint32_t, f);
  uint32_t r = u + 0x7FFFu + ((u >> 16) & 1u);
  return (unsigned short)(r >> 16);
}
__device__ __forceinline__ float bf2f(unsigned short u) {
  return __builtin_bit_cast(float, (uint32_t)u << 16);
}

// ---- integer degree counts: cnt[0..3NN) = out-deg per rel, cnt[3NN..6NN) = in-deg ----
__global__ void cnt_kernel(const int* __restrict__ es, const int* __restrict__ ed,
                           int* __restrict__ cnt) {
  int i = blockIdx.x * blockDim.x + threadIdx.x;
  if (i >= NREL * NE) return;
  int r = i / NE;
  atomicAdd(&cnt[r * NN + es[i]], 1);
  atomicAdd(&cnt[NREL * NN + r * NN + ed[i]], 1);
}

// rs[i] = rsqrt(max(cnt[i],1)) for both out and in halves
__global__ void rs_kernel(const int* __restrict__ cnt, float* __restrict__ rs) {
  int i = blockIdx.x * blockDim.x + threadIdx.x;
  if (i >= 2 * NREL * NN) return;
  rs[i] = rsqrtf((float)max(cnt[i], 1));
}

// per (rel,node) dst-bucket start offsets: wave-scan + 1 atomic per wave
__global__ void bucket_kernel(const int* __restrict__ cnt_in, int* __restrict__ start,
                              int* __restrict__ fill, int* __restrict__ cursor) {
  int i = blockIdx.x * blockDim.x + threadIdx.x;
  int lane = threadIdx.x & 63;
  int v = (i < NREL * NN) ? cnt_in[i] : 0;
  int s = v;
#pragma unroll
  for (int d = 1; d < 64; d <<= 1) {
    int o = __shfl_up(s, d);
    if (lane >= d) s += o;
  }
  int total = __shfl(s, 63);
  int base = 0;
  if (lane == 63) base = atomicAdd(cursor, total);
  base = __shfl(base, 63);
  if (i < NREL * NN) {
    start[i] = base + s - v;
    fill[i] = 0;
  }
}

// place each edge's (rel*NN + src) into its dst bucket
__global__ void fill_kernel(const int* __restrict__ es, const int* __restrict__ ed,
                            const int* __restrict__ start, int* __restrict__ fill,
                            int* __restrict__ epay) {
  int i = blockIdx.x * blockDim.x + threadIdx.x;
  if (i >= NREL * NE) return;
  int r = i / NE;
  int b = r * NN + ed[i];
  int pos = start[b] + atomicAdd(&fill[b], 1);
  epay[pos] = r * NN + es[i];
}

// Wtb[layer][rel][n][k] = bf16(W[layer][rel][k][n])
__global__ void wcvt_kernel(const float* __restrict__ W1, const float* __restrict__ W2,
                            unsigned short* __restrict__ Wtb) {
  int i = blockIdx.x * blockDim.x + threadIdx.x;
  if (i >= 2 * NREL * F * F) return;
  int l = i / (NREL * F * F);
  int rem = i % (NREL * F * F);
  int r = rem / (F * F);
  int nk = rem % (F * F);
  int n = nk >> 7, k = nk & 127;
  const float* W = l ? W2 : W1;
  Wtb[i] = f2bf(W[r * F * F + k * F + n]);
}

// bsum[l][f] = sum_r b_l[r][f]
__global__ void bias_kernel(const float* __restrict__ b1, const float* __restrict__ b2,
                            float* __restrict__ bsum) {
  int t = threadIdx.x;  // 256
  int l = t >> 7, f = t & 127;
  const float* b = l ? b2 : b1;
  bsum[l * F + f] = b[f] + b[F + f] + b[2 * F + f];
}

// X (f32) -> Xb (bf16)
__global__ void cvtx_kernel(const float* __restrict__ x, unsigned short* __restrict__ xb) {
  int i = blockIdx.x * blockDim.x + threadIdx.x;  // one per 8 elems
  const float* p = x + (size_t)i * 8;
  unsigned short tmp[8];
#pragma unroll
  for (int e = 0; e < 8; ++e) tmp[e] = f2bf(p[e]);
  *reinterpret_cast<u16x8*>(xb + (size_t)i * 8) = *reinterpret_cast<u16x8*>(tmp);
}

// y[M,128] = bf16( rs_out[m] * (Xb[M,128] @ W[128,128]) ), blockIdx.y = relation
#define BM 64
#define LDP 136
__global__ __launch_bounds__(256) void gemm_kernel(const unsigned short* __restrict__ Xb,
                                                   const unsigned short* __restrict__ Wtb,
                                                   const float* __restrict__ rs_out_all,
                                                   unsigned short* __restrict__ ybuf,
                                                   int nrows) {
  const int rel = blockIdx.y;
  const unsigned short* Wt = Wtb + (size_t)rel * F * F;
  const float* rs_out = rs_out_all + (size_t)rel * NN;
  unsigned short* y = ybuf + (size_t)rel * NN * F;

  __shared__ unsigned short A_lds[BM * LDP];
  __shared__ unsigned short W_lds[F * LDP];
  const int t = threadIdx.x;
  const int m0 = blockIdx.x * BM;

#pragma unroll
  for (int i = 0; i < 8; ++i) {
    int c = t + i * 256;
    int n = c >> 4, kc = (c & 15) * 8;
    *reinterpret_cast<u16x8*>(&W_lds[n * LDP + kc]) =
        *reinterpret_cast<const u16x8*>(Wt + n * F + kc);
  }
#pragma unroll
  for (int i = 0; i < 4; ++i) {
    int c = t + i * 256;
    int row = c >> 4, cg = (c & 15) * 8;
    int gm = m0 + row;
    u16x8 v;
    if (gm < nrows) {
      v = *reinterpret_cast<const u16x8*>(Xb + (size_t)gm * F + cg);
    } else {
      v = (u16x8)0;
    }
    *reinterpret_cast<u16x8*>(&A_lds[row * LDP + cg]) = v;
  }
  __syncthreads();

  const int lane = t & 63, w = t >> 6;
  const int r0 = lane & 15, kq = lane >> 4;
  fx4 acc[8];
#pragma unroll
  for (int nt = 0; nt < 8; ++nt) acc[nt] = (fx4){0.f, 0.f, 0.f, 0.f};

  const unsigned short* ap = &A_lds[(w * 16 + r0) * LDP + kq * 8];
  const unsigned short* bp = &W_lds[r0 * LDP + kq * 8];
#pragma unroll
  for (int kb = 0; kb < 4; ++kb) {
    bf16x8 a = __builtin_bit_cast(bf16x8, *reinterpret_cast<const u16x8*>(ap + kb * 32));
#pragma unroll
    for (int nt = 0; nt < 8; ++nt) {
      bf16x8 b = __builtin_bit_cast(bf16x8,
          *reinterpret_cast<const u16x8*>(bp + nt * 16 * LDP + kb * 32));
      acc[nt] = __builtin_amdgcn_mfma_f32_16x16x32_bf16(a, b, acc[nt], 0, 0, 0);
    }
  }
  // C/D layout: col = lane&15, row = (lane>>4)*4 + reg
  const int rbase = m0 + w * 16 + kq * 4;
  float sc[4];
#pragma unroll
  for (int reg = 0; reg < 4; ++reg)
    sc[reg] = (rbase + reg < nrows) ? rs_out[rbase + reg] : 0.f;
#pragma unroll
  for (int nt = 0; nt < 8; ++nt) {
    int col = nt * 16 + r0;
#pragma unroll
    for (int reg = 0; reg < 4; ++reg) {
      int gm = rbase + reg;
      if (gm < nrows) y[(size_t)gm * F + col] = f2bf(acc[nt][reg] * sc[reg]);
    }
  }
}

// ---- fused aggregate core: one WAVE per node ----
// lane: eslot = lane>>4 (4 edges in flight), j = lane&15 (features j*8..j*8+7, u16x8 load)
// tot[8] = sum_r rs_in_r[n] * sum_edges row + bias; v = tanh(tot)
__device__ __forceinline__ void agg_node(int n, const unsigned short* __restrict__ ybuf,
                                         const int* __restrict__ start,
                                         const int* __restrict__ cnt_in,
                                         const int* __restrict__ epay,
                                         const float* __restrict__ rs_in,
                                         const float* __restrict__ bsum,
                                         float out_v[8], int j, int eslot) {
  float tot[8];
#pragma unroll
  for (int k = 0; k < 8; ++k) tot[k] = 0.f;
#pragma unroll
  for (int r = 0; r < NREL; ++r) {
    int base = r * NN + n;
    int s0 = start[base];
    int c = cnt_in[base];
    float s = rs_in[base];
    float ps[8];
#pragma unroll
    for (int k = 0; k < 8; ++k) ps[k] = 0.f;
    for (int i = eslot; i < c; i += 4) {
      int p = epay[s0 + i];
      u16x8 v = *reinterpret_cast<const u16x8*>(ybuf + ((size_t)p << 7) + j * 8);
#pragma unroll
      for (int k = 0; k < 8; ++k) ps[k] += bf2f(v[k]);
    }
#pragma unroll
    for (int k = 0; k < 8; ++k) tot[k] += ps[k] * s;
  }
  // reduce across the 4 eslots
#pragma unroll
  for (int k = 0; k < 8; ++k) {
    tot[k] += __shfl_xor(tot[k], 16);
    tot[k] += __shfl_xor(tot[k], 32);
  }
#pragma unroll
  for (int k = 0; k < 8; ++k) out_v[k] = tanhf(tot[k] + bsum[j * 8 + k]);
}

// layer-1: all nodes, write bf16 Xb (input of layer-2 GEMM)
__global__ __launch_bounds__(256) void agg1_kernel(const unsigned short* __restrict__ ybuf,
                                                   const int* __restrict__ start,
                                                   const int* __restrict__ cnt_in,
                                                   const int* __restrict__ epay,
                                                   const float* __restrict__ rs_in,
                                                   const float* __restrict__ bsum,
                                                   unsigned short* __restrict__ xbout) {
  int t = threadIdx.x;
  int n = blockIdx.x * 4 + (t >> 6);
  int lane = t & 63, j = lane & 15, eslot = lane >> 4;
  float v[8];
  agg_node(n, ybuf, start, cnt_in, epay, rs_in, bsum, v, j, eslot);
  if (lane < 16) {
    unsigned short tmp[8];
#pragma unroll
    for (int k = 0; k < 8; ++k) tmp[k] = f2bf(v[k]);
    *reinterpret_cast<u16x8*>(xbout + (size_t)n * F + j * 8) =
        *reinterpret_cast<u16x8*>(tmp);
  }
}

// layer-2: only the 2*NQ query slots, write f32 directly to d_out
__global__ __launch_bounds__(256) void agg2_kernel(const unsigned short* __restrict__ ybuf,
                                                   const int* __restrict__ start,
                                                   const int* __restrict__ cnt_in,
                                                   const int* __restrict__ epay,
                                                   const float* __restrict__ rs_in,
                                                   const float* __restrict__ bsum,
                                                   const int* __restrict__ qsrc,
                                                   const int* __restrict__ qdst,
                                                   float* __restrict__ out) {
  int t = threadIdx.x;
  int q = blockIdx.x * 4 + (t >> 6);  // 0..2*NQ
  int lane = t & 63, j = lane & 15, eslot = lane >> 4;
  int n = (q < NQ) ? qsrc[q] : qdst[q - NQ];
  float v[8];
  agg_node(n, ybuf, start, cnt_in, epay, rs_in, bsum, v, j, eslot);
  if (lane < 16) {
    fx4 lo = {v[0], v[1], v[2], v[3]}, hi = {v[4], v[5], v[6], v[7]};
    float* op = out + (size_t)q * F + j * 8;
    *reinterpret_cast<fx4*>(op) = lo;
    *reinterpret_cast<fx4*>(op + 4) = hi;
  }
}

extern "C" void kernel_launch(void* const* d_in, const int* in_sizes, int n_in,
                              void* d_out, int out_size, void* d_ws, size_t ws_size,
                              hipStream_t stream) {
  const float* emb = (const float*)d_in[0];
  const float* W1  = (const float*)d_in[1];
  const float* b1  = (const float*)d_in[2];
  const float* W2  = (const float*)d_in[3];
  const float* b2  = (const float*)d_in[4];
  const int* e_src = (const int*)d_in[5];
  const int* e_dst = (const int*)d_in[6];
  const int* qsrc  = (const int*)d_in[7];
  const int* qdst  = (const int*)d_in[8];
  float* out = (float*)d_out;

  char* p = (char*)d_ws;
  size_t off = 0;
  auto take = [&](size_t n) { void* q = p + off; off = (off + n + 255) & ~(size_t)255; return q; };
  int* cnt    = (int*)take(2ull * NREL * NN * 4 + 4);   // [out|in] counts + cursor tail
  int* cursor = cnt + 2 * NREL * NN;
  float* rs   = (float*)take(2ull * NREL * NN * 4);     // rsqrt of [out|in]
  int* start  = (int*)take((size_t)NREL * NN * 4);
  int* fill   = (int*)take((size_t)NREL * NN * 4);
  int* epay   = (int*)take((size_t)NREL * NE * 4);
  unsigned short* Wtb = (unsigned short*)take(2ull * NREL * F * F * 2);
  float* bsum = (float*)take(2ull * F * 4);
  unsigned short* Xb  = (unsigned short*)take((size_t)NN * F * 2);
  unsigned short* ybuf = (unsigned short*)take((size_t)NREL * NN * F * 2);

  float* rs_out = rs;
  float* rs_in  = rs + (size_t)NREL * NN;
  int* cnt_in   = cnt + (size_t)NREL * NN;

  hipMemsetAsync(cnt, 0, 2ull * NREL * NN * 4 + 4, stream);
  cnt_kernel<<<(NREL * NE + 255) / 256, 256, 0, stream>>>(e_src, e_dst, cnt);
  rs_kernel<<<(2 * NREL * NN + 255) / 256, 256, 0, stream>>>(cnt, rs);
  bucket_kernel<<<(NREL * NN + 255) / 256, 256, 0, stream>>>(cnt_in, start, fill, cursor);
  fill_kernel<<<(NREL * NE + 255) / 256, 256, 0, stream>>>(e_src, e_dst, start, fill, epay);
  wcvt_kernel<<<(2 * NREL * F * F + 255) / 256, 256, 0, stream>>>(W1, W2, Wtb);
  bias_kernel<<<1, 256, 0, stream>>>(b1, b2, bsum);
  cvtx_kernel<<<(NN * F / 8 + 255) / 256, 256, 0, stream>>>(emb, Xb);

  dim3 ggrid((NN + BM - 1) / BM, NREL);
  // layer 1
  gemm_kernel<<<ggrid, 256, 0, stream>>>(Xb, Wtb, rs_out, ybuf, NN);
  agg1_kernel<<<NN / 4, 256, 0, stream>>>(ybuf, start, cnt_in, epay, rs_in, bsum, Xb);
  // layer 2
  gemm_kernel<<<ggrid, 256, 0, stream>>>(Xb, Wtb + (size_t)NREL * F * F, rs_out, ybuf, NN);
  agg2_kernel<<<2 * NQ / 4, 256, 0, stream>>>(ybuf, start, cnt_in, epay, rs_in,
                                              bsum + F, qsrc, qdst, out);
}

// Round 4
// 330.527 us; speedup vs baseline: 2.4000x; 1.2235x over previous
//
#include <hip/hip_runtime.h>
#include <stdint.h>

#define NN 100000   // nodes
#define NREL 3
#define NE 200000   // edges per relation
#define F 128       // feature dim (in = hid = out)
#define NQ 4096

typedef float fx4 __attribute__((ext_vector_type(4)));
typedef unsigned short u16x8 __attribute__((ext_vector_type(8)));
typedef __bf16 bf16x8 __attribute__((ext_vector_type(8)));

__device__ __forceinline__ unsigned short f2bf(float f) {
  uint32_t u = __builtin_bit_cast(uint32_t, f);
  uint32_t r = u + 0x7FFFu + ((u >> 16) & 1u);
  return (unsigned short)(r >> 16);
}
__device__ __forceinline__ float bf2f(unsigned short u) {
  return __builtin_bit_cast(float, (uint32_t)u << 16);
}

// ---- integer degree counts: cnt[0..3NN) = out-deg per rel, cnt[3NN..6NN) = in-deg ----
__global__ void cnt_kernel(const int* __restrict__ es, const int* __restrict__ ed,
                           int* __restrict__ cnt) {
  int i = blockIdx.x * blockDim.x + threadIdx.x;
  if (i >= NREL * NE) return;
  int r = i / NE;
  atomicAdd(&cnt[r * NN + es[i]], 1);
  atomicAdd(&cnt[NREL * NN + r * NN + ed[i]], 1);
}

// rs[i] = rsqrt(max(cnt[i],1)) for both out and in halves
__global__ void rs_kernel(const int* __restrict__ cnt, float* __restrict__ rs) {
  int i = blockIdx.x * blockDim.x + threadIdx.x;
  if (i >= 2 * NREL * NN) return;
  rs[i] = rsqrtf((float)max(cnt[i], 1));
}

// per (rel,node) dst-bucket start offsets: wave-scan + 1 atomic per wave
__global__ void bucket_kernel(const int* __restrict__ cnt_in, int* __restrict__ start,
                              int* __restrict__ fill, int* __restrict__ cursor) {
  int i = blockIdx.x * blockDim.x + threadIdx.x;
  int lane = threadIdx.x & 63;
  int v = (i < NREL * NN) ? cnt_in[i] : 0;
  int s = v;
#pragma unroll
  for (int d = 1; d < 64; d <<= 1) {
    int o = __shfl_up(s, d);
    if (lane >= d) s += o;
  }
  int total = __shfl(s, 63);
  int base = 0;
  if (lane == 63) base = atomicAdd(cursor, total);
  base = __shfl(base, 63);
  if (i < NREL * NN) {
    start[i] = base + s - v;
    fill[i] = 0;
  }
}

// place each edge's (rel*NN + src) into its dst bucket
__global__ void fill_kernel(const int* __restrict__ es, const int* __restrict__ ed,
                            const int* __restrict__ start, int* __restrict__ fill,
                            int* __restrict__ epay) {
  int i = blockIdx.x * blockDim.x + threadIdx.x;
  if (i >= NREL * NE) return;
  int r = i / NE;
  int b = r * NN + ed[i];
  int pos = start[b] + atomicAdd(&fill[b], 1);
  epay[pos] = r * NN + es[i];
}

// Wtb[layer][rel][n][k] = bf16(W[layer][rel][k][n])
__global__ void wcvt_kernel(const float* __restrict__ W1, const float* __restrict__ W2,
                            unsigned short* __restrict__ Wtb) {
  int i = blockIdx.x * blockDim.x + threadIdx.x;
  if (i >= 2 * NREL * F * F) return;
  int l = i / (NREL * F * F);
  int rem = i % (NREL * F * F);
  int r = rem / (F * F);
  int nk = rem % (F * F);
  int n = nk >> 7, k = nk & 127;
  const float* W = l ? W2 : W1;
  Wtb[i] = f2bf(W[r * F * F + k * F + n]);
}

// bsum[l][f] = sum_r b_l[r][f]
__global__ void bias_kernel(const float* __restrict__ b1, const float* __restrict__ b2,
                            float* __restrict__ bsum) {
  int t = threadIdx.x;  // 256
  int l = t >> 7, f = t & 127;
  const float* b = l ? b2 : b1;
  bsum[l * F + f] = b[f] + b[F + f] + b[2 * F + f];
}

// X (f32) -> Xb (bf16)
__global__ void cvtx_kernel(const float* __restrict__ x, unsigned short* __restrict__ xb) {
  int i = blockIdx.x * blockDim.x + threadIdx.x;  // one per 8 elems
  const float* p = x + (size_t)i * 8;
  unsigned short tmp[8];
#pragma unroll
  for (int e = 0; e < 8; ++e) tmp[e] = f2bf(p[e]);
  *reinterpret_cast<u16x8*>(xb + (size_t)i * 8) = *reinterpret_cast<u16x8*>(tmp);
}

// ---- aggregate-first: Z[r][m][f] = rs_in_r[n] * sum_{e in bucket(r,n)} rs_out_r[src] * X[src][f]
// one WAVE per (rel, m): eslot = lane>>4 (4 edges in flight), j = lane&15 (u16x8 feature octet)
// layer1: m == node n (M=NN, qsrc/qdst null). layer2: n = query[m] (M=2*NQ).
__global__ __launch_bounds__(256) void aggz_kernel(const unsigned short* __restrict__ X,
                                                   const int* __restrict__ start,
                                                   const int* __restrict__ cnt_in,
                                                   const int* __restrict__ epay,
                                                   const float* __restrict__ rs_out,
                                                   const float* __restrict__ rs_in,
                                                   const int* __restrict__ qsrc,
                                                   const int* __restrict__ qdst,
                                                   unsigned short* __restrict__ Z, int M) {
  const int r = blockIdx.y;
  int t = threadIdx.x;
  int m = blockIdx.x * 4 + (t >> 6);
  if (m >= M) return;
  int lane = t & 63, j = lane & 15, eslot = lane >> 4;
  int n = qsrc ? ((m < NQ) ? qsrc[m] : qdst[m - NQ]) : m;
  int base = r * NN + n;
  int s0 = start[base];
  int c = cnt_in[base];
  float ps[8];
#pragma unroll
  for (int k = 0; k < 8; ++k) ps[k] = 0.f;
  for (int i = eslot; i < c; i += 4) {
    int p = epay[s0 + i];          // p = r*NN + src
    float so = rs_out[p];
    int src = p - r * NN;
    u16x8 v = *reinterpret_cast<const u16x8*>(X + ((size_t)src << 7) + j * 8);
#pragma unroll
    for (int k = 0; k < 8; ++k) ps[k] += bf2f(v[k]) * so;
  }
#pragma unroll
  for (int k = 0; k < 8; ++k) {
    ps[k] += __shfl_xor(ps[k], 16);
    ps[k] += __shfl_xor(ps[k], 32);
  }
  if (lane < 16) {
    float si = rs_in[base];
    unsigned short tmp[8];
#pragma unroll
    for (int k = 0; k < 8; ++k) tmp[k] = f2bf(ps[k] * si);
    *reinterpret_cast<u16x8*>(Z + (((size_t)r * M + m) << 7) + j * 8) =
        *reinterpret_cast<u16x8*>(tmp);
  }
}

// fused K=384 GEMM: out[m] = tanh( sum_r Z[r][m] @ W_r + bsum )
// BM=64 rows per block, 4 waves (wave w -> rows w*16..), N=128 full.
#define BM 64
#define LDP 136
__global__ __launch_bounds__(256) void gemmf_kernel(const unsigned short* __restrict__ Z,
                                                    const unsigned short* __restrict__ Wt3,
                                                    const float* __restrict__ bsum,
                                                    void* __restrict__ outp,
                                                    int M, int out_f32) {
  __shared__ unsigned short A_lds[BM * LDP];
  __shared__ unsigned short W_lds[F * LDP];
  const int t = threadIdx.x;
  const int m0 = blockIdx.x * BM;
  const int lane = t & 63, w = t >> 6;
  const int r0 = lane & 15, kq = lane >> 4;

  fx4 acc[8];
#pragma unroll
  for (int nt = 0; nt < 8; ++nt) acc[nt] = (fx4){0.f, 0.f, 0.f, 0.f};

  for (int r = 0; r < NREL; ++r) {
    __syncthreads();  // previous chunk's LDS reads done
    const unsigned short* Wt = Wt3 + (size_t)r * F * F;
#pragma unroll
    for (int i = 0; i < 8; ++i) {
      int c = t + i * 256;
      int n = c >> 4, kc = (c & 15) * 8;
      *reinterpret_cast<u16x8*>(&W_lds[n * LDP + kc]) =
          *reinterpret_cast<const u16x8*>(Wt + n * F + kc);
    }
#pragma unroll
    for (int i = 0; i < 4; ++i) {
      int c = t + i * 256;
      int row = c >> 4, cg = (c & 15) * 8;
      int gm = m0 + row;
      u16x8 v;
      if (gm < M) {
        v = *reinterpret_cast<const u16x8*>(Z + (((size_t)r * M + gm) << 7) + cg);
      } else {
        v = (u16x8)0;
      }
      *reinterpret_cast<u16x8*>(&A_lds[row * LDP + cg]) = v;
    }
    __syncthreads();

    const unsigned short* ap = &A_lds[(w * 16 + r0) * LDP + kq * 8];
    const unsigned short* bp = &W_lds[r0 * LDP + kq * 8];
#pragma unroll
    for (int kb = 0; kb < 4; ++kb) {
      bf16x8 a = __builtin_bit_cast(bf16x8, *reinterpret_cast<const u16x8*>(ap + kb * 32));
#pragma unroll
      for (int nt = 0; nt < 8; ++nt) {
        bf16x8 b = __builtin_bit_cast(bf16x8,
            *reinterpret_cast<const u16x8*>(bp + nt * 16 * LDP + kb * 32));
        acc[nt] = __builtin_amdgcn_mfma_f32_16x16x32_bf16(a, b, acc[nt], 0, 0, 0);
      }
    }
  }

  // C/D layout: col = lane&15, row = (lane>>4)*4 + reg; epilogue: +bias, tanh
  const int rbase = m0 + w * 16 + kq * 4;
#pragma unroll
  for (int nt = 0; nt < 8; ++nt) {
    int col = nt * 16 + r0;
    float bb = bsum[col];
#pragma unroll
    for (int reg = 0; reg < 4; ++reg) {
      int gm = rbase + reg;
      if (gm < M) {
        float v = tanhf(acc[nt][reg] + bb);
        if (out_f32) {
          ((float*)outp)[(size_t)gm * F + col] = v;
        } else {
          ((unsigned short*)outp)[(size_t)gm * F + col] = f2bf(v);
        }
      }
    }
  }
}

extern "C" void kernel_launch(void* const* d_in, const int* in_sizes, int n_in,
                              void* d_out, int out_size, void* d_ws, size_t ws_size,
                              hipStream_t stream) {
  const float* emb = (const float*)d_in[0];
  const float* W1  = (const float*)d_in[1];
  const float* b1  = (const float*)d_in[2];
  const float* W2  = (const float*)d_in[3];
  const float* b2  = (const float*)d_in[4];
  const int* e_src = (const int*)d_in[5];
  const int* e_dst = (const int*)d_in[6];
  const int* qsrc  = (const int*)d_in[7];
  const int* qdst  = (const int*)d_in[8];
  float* out = (float*)d_out;

  char* p = (char*)d_ws;
  size_t off = 0;
  auto take = [&](size_t n) { void* q = p + off; off = (off + n + 255) & ~(size_t)255; return q; };
  int* cnt    = (int*)take(2ull * NREL * NN * 4 + 4);   // [out|in] counts + cursor tail
  int* cursor = cnt + 2 * NREL * NN;
  float* rs   = (float*)take(2ull * NREL * NN * 4);     // rsqrt of [out|in]
  int* start  = (int*)take((size_t)NREL * NN * 4);
  int* fill   = (int*)take((size_t)NREL * NN * 4);
  int* epay   = (int*)take((size_t)NREL * NE * 4);
  unsigned short* Wtb = (unsigned short*)take(2ull * NREL * F * F * 2);
  float* bsum = (float*)take(2ull * F * 4);
  unsigned short* Xb  = (unsigned short*)take((size_t)NN * F * 2);
  unsigned short* Z   = (unsigned short*)take((size_t)NREL * NN * F * 2);  // layer1 Z / layer2 Z2q fits too

  float* rs_out = rs;
  float* rs_in  = rs + (size_t)NREL * NN;
  int* cnt_in   = cnt + (size_t)NREL * NN;

  hipMemsetAsync(cnt, 0, 2ull * NREL * NN * 4 + 4, stream);
  cnt_kernel<<<(NREL * NE + 255) / 256, 256, 0, stream>>>(e_src, e_dst, cnt);
  rs_kernel<<<(2 * NREL * NN + 255) / 256, 256, 0, stream>>>(cnt, rs);
  bucket_kernel<<<(NREL * NN + 255) / 256, 256, 0, stream>>>(cnt_in, start, fill, cursor);
  fill_kernel<<<(NREL * NE + 255) / 256, 256, 0, stream>>>(e_src, e_dst, start, fill, epay);
  wcvt_kernel<<<(2 * NREL * F * F + 255) / 256, 256, 0, stream>>>(W1, W2, Wtb);
  bias_kernel<<<1, 256, 0, stream>>>(b1, b2, bsum);
  cvtx_kernel<<<(NN * F / 8 + 255) / 256, 256, 0, stream>>>(emb, Xb);

  // layer 1: Z1 at all nodes, fused GEMM writes bf16 h1 back into Xb
  dim3 ag1((NN + 3) / 4, NREL);
  aggz_kernel<<<ag1, 256, 0, stream>>>(Xb, start, cnt_in, epay, rs_out, rs_in,
                                       nullptr, nullptr, Z, NN);
  gemmf_kernel<<<(NN + BM - 1) / BM, 256, 0, stream>>>(Z, Wtb, bsum, Xb, NN, 0);

  // layer 2: only the 2*NQ query slots
  dim3 ag2((2 * NQ + 3) / 4, NREL);
  aggz_kernel<<<ag2, 256, 0, stream>>>(Xb, start, cnt_in, epay, rs_out, rs_in,
                                       qsrc, qdst, Z, 2 * NQ);
  gemmf_kernel<<<(2 * NQ + BM - 1) / BM, 256, 0, stream>>>(
      Z, Wtb + (size_t)NREL * F * F, bsum + F, out, 2 * NQ, 1);
}

// Round 5
// 273.174 us; speedup vs baseline: 2.9039x; 1.2100x over previous
//
#include <hip/hip_runtime.h>
#include <stdint.h>

#define NN 100000   // nodes
#define NREL 3
#define NE 200000   // edges per relation
#define F 128       // feature dim (in = hid = out)
#define NQ 4096

typedef float fx4 __attribute__((ext_vector_type(4)));
typedef unsigned short u16x8 __attribute__((ext_vector_type(8)));
typedef __bf16 bf16x8 __attribute__((ext_vector_type(8)));

__device__ __forceinline__ unsigned short f2bf(float f) {
  uint32_t u = __builtin_bit_cast(uint32_t, f);
  uint32_t r = u + 0x7FFFu + ((u >> 16) & 1u);
  return (unsigned short)(r >> 16);
}
__device__ __forceinline__ float bf2f(unsigned short u) {
  return __builtin_bit_cast(float, (uint32_t)u << 16);
}

// ---- integer degree counts: cnt[0..3NN) = out-deg per rel, cnt[3NN..6NN) = in-deg ----
__global__ void cnt_kernel(const int* __restrict__ es, const int* __restrict__ ed,
                           int* __restrict__ cnt) {
  int i = blockIdx.x * blockDim.x + threadIdx.x;
  if (i >= NREL * NE) return;
  int r = i / NE;
  atomicAdd(&cnt[r * NN + es[i]], 1);
  atomicAdd(&cnt[NREL * NN + r * NN + ed[i]], 1);
}

// rs[i] = rsqrt(max(cnt[i],1)) for both out and in halves
__global__ void rs_kernel(const int* __restrict__ cnt, float* __restrict__ rs) {
  int i = blockIdx.x * blockDim.x + threadIdx.x;
  if (i >= 2 * NREL * NN) return;
  rs[i] = rsqrtf((float)max(cnt[i], 1));
}

// per (rel,node) dst-bucket: sc[i] = {start, cnt}; wave-scan + 1 atomic per wave
__global__ void bucket_kernel(const int* __restrict__ cnt_in, int2* __restrict__ sc,
                              int* __restrict__ fill, int* __restrict__ cursor) {
  int i = blockIdx.x * blockDim.x + threadIdx.x;
  int lane = threadIdx.x & 63;
  int v = (i < NREL * NN) ? cnt_in[i] : 0;
  int s = v;
#pragma unroll
  for (int d = 1; d < 64; d <<= 1) {
    int o = __shfl_up(s, d);
    if (lane >= d) s += o;
  }
  int total = __shfl(s, 63);
  int base = 0;
  if (lane == 63) base = atomicAdd(cursor, total);
  base = __shfl(base, 63);
  if (i < NREL * NN) {
    sc[i] = make_int2(base + s - v, v);
    fill[i] = 0;
  }
}

// place each edge into its dst bucket; payload = {src, w = rs_out[src]*rs_in[dst]}
__global__ void fill_kernel(const int* __restrict__ es, const int* __restrict__ ed,
                            const int2* __restrict__ sc, int* __restrict__ fill,
                            const float* __restrict__ rs_out,
                            const float* __restrict__ rs_in,
                            int2* __restrict__ epay) {
  int i = blockIdx.x * blockDim.x + threadIdx.x;
  if (i >= NREL * NE) return;
  int r = i / NE;
  int s = es[i], d = ed[i];
  int b = r * NN + d;
  int pos = sc[b].x + atomicAdd(&fill[b], 1);
  float w = rs_out[r * NN + s] * rs_in[b];
  epay[pos] = make_int2(s, __builtin_bit_cast(int, w));
}

// Wtb[layer][rel][n][k] = bf16(W[layer][rel][k][n])
__global__ void wcvt_kernel(const float* __restrict__ W1, const float* __restrict__ W2,
                            unsigned short* __restrict__ Wtb) {
  int i = blockIdx.x * blockDim.x + threadIdx.x;
  if (i >= 2 * NREL * F * F) return;
  int l = i / (NREL * F * F);
  int rem = i % (NREL * F * F);
  int r = rem / (F * F);
  int nk = rem % (F * F);
  int n = nk >> 7, k = nk & 127;
  const float* W = l ? W2 : W1;
  Wtb[i] = f2bf(W[r * F * F + k * F + n]);
}

// bsum[l][f] = sum_r b_l[r][f]
__global__ void bias_kernel(const float* __restrict__ b1, const float* __restrict__ b2,
                            float* __restrict__ bsum) {
  int t = threadIdx.x;  // 256
  int l = t >> 7, f = t & 127;
  const float* b = l ? b2 : b1;
  bsum[l * F + f] = b[f] + b[F + f] + b[2 * F + f];
}

// X (f32) -> Xb (bf16)
__global__ void cvtx_kernel(const float* __restrict__ x, unsigned short* __restrict__ xb) {
  int i = blockIdx.x * blockDim.x + threadIdx.x;  // one per 8 elems
  const float* p = x + (size_t)i * 8;
  unsigned short tmp[8];
#pragma unroll
  for (int e = 0; e < 8; ++e) tmp[e] = f2bf(p[e]);
  *reinterpret_cast<u16x8*>(xb + (size_t)i * 8) = *reinterpret_cast<u16x8*>(tmp);
}

// ---- aggregate-first: Z[r][m][f] = sum_{e in bucket(r,n)} w_e * X[src_e][f]
// 16 lanes per m-row (j = lane&15 -> features j*8..j*8+7), 4 rows per wave, no cross-lane ops.
// layer1: n == m (M=NN). layer2: n = query[m] (M=2*NQ).
__global__ __launch_bounds__(256) void aggz_kernel(const unsigned short* __restrict__ X,
                                                   const int2* __restrict__ sc,
                                                   const int2* __restrict__ epay,
                                                   const int* __restrict__ qsrc,
                                                   const int* __restrict__ qdst,
                                                   unsigned short* __restrict__ Z, int M) {
  const int r = blockIdx.y;
  const int t = threadIdx.x;
  const int lane = t & 63;
  const int m = blockIdx.x * 16 + (t >> 6) * 4 + (lane >> 4);
  const int j = lane & 15;
  if (m >= M) return;
  int n = qsrc ? ((m < NQ) ? qsrc[m] : qdst[m - NQ]) : m;
  int2 meta = sc[r * NN + n];
  const int2* ep = epay + meta.x;
  const int c = meta.y;

  float ps[8];
#pragma unroll
  for (int k = 0; k < 8; ++k) ps[k] = 0.f;

  int i = 0;
  for (; i + 2 <= c; i += 2) {
    int2 p0 = ep[i], p1 = ep[i + 1];
    float w0 = __builtin_bit_cast(float, p0.y);
    float w1 = __builtin_bit_cast(float, p1.y);
    u16x8 v0 = *reinterpret_cast<const u16x8*>(X + ((size_t)p0.x << 7) + j * 8);
    u16x8 v1 = *reinterpret_cast<const u16x8*>(X + ((size_t)p1.x << 7) + j * 8);
#pragma unroll
    for (int k = 0; k < 8; ++k)
      ps[k] = fmaf(bf2f(v1[k]), w1, fmaf(bf2f(v0[k]), w0, ps[k]));
  }
  if (i < c) {
    int2 p0 = ep[i];
    float w0 = __builtin_bit_cast(float, p0.y);
    u16x8 v0 = *reinterpret_cast<const u16x8*>(X + ((size_t)p0.x << 7) + j * 8);
#pragma unroll
    for (int k = 0; k < 8; ++k) ps[k] = fmaf(bf2f(v0[k]), w0, ps[k]);
  }

  unsigned short tmp[8];
#pragma unroll
  for (int k = 0; k < 8; ++k) tmp[k] = f2bf(ps[k]);
  *reinterpret_cast<u16x8*>(Z + (((size_t)r * M + m) << 7) + j * 8) =
      *reinterpret_cast<u16x8*>(tmp);
}

// fused K=384 GEMM: out[m] = tanh( sum_r Z[r][m] @ W_r + bsum )
#define BM 64
#define LDP 136
__global__ __launch_bounds__(256) void gemmf_kernel(const unsigned short* __restrict__ Z,
                                                    const unsigned short* __restrict__ Wt3,
                                                    const float* __restrict__ bsum,
                                                    void* __restrict__ outp,
                                                    int M, int out_f32) {
  __shared__ unsigned short A_lds[BM * LDP];
  __shared__ unsigned short W_lds[F * LDP];
  const int t = threadIdx.x;
  const int m0 = blockIdx.x * BM;
  const int lane = t & 63, w = t >> 6;
  const int r0 = lane & 15, kq = lane >> 4;

  fx4 acc[8];
#pragma unroll
  for (int nt = 0; nt < 8; ++nt) acc[nt] = (fx4){0.f, 0.f, 0.f, 0.f};

  for (int r = 0; r < NREL; ++r) {
    __syncthreads();  // previous chunk's LDS reads done
    const unsigned short* Wt = Wt3 + (size_t)r * F * F;
#pragma unroll
    for (int i = 0; i < 8; ++i) {
      int c = t + i * 256;
      int n = c >> 4, kc = (c & 15) * 8;
      *reinterpret_cast<u16x8*>(&W_lds[n * LDP + kc]) =
          *reinterpret_cast<const u16x8*>(Wt + n * F + kc);
    }
#pragma unroll
    for (int i = 0; i < 4; ++i) {
      int c = t + i * 256;
      int row = c >> 4, cg = (c & 15) * 8;
      int gm = m0 + row;
      u16x8 v;
      if (gm < M) {
        v = *reinterpret_cast<const u16x8*>(Z + (((size_t)r * M + gm) << 7) + cg);
      } else {
        v = (u16x8)0;
      }
      *reinterpret_cast<u16x8*>(&A_lds[row * LDP + cg]) = v;
    }
    __syncthreads();

    const unsigned short* ap = &A_lds[(w * 16 + r0) * LDP + kq * 8];
    const unsigned short* bp = &W_lds[r0 * LDP + kq * 8];
#pragma unroll
    for (int kb = 0; kb < 4; ++kb) {
      bf16x8 a = __builtin_bit_cast(bf16x8, *reinterpret_cast<const u16x8*>(ap + kb * 32));
#pragma unroll
      for (int nt = 0; nt < 8; ++nt) {
        bf16x8 b = __builtin_bit_cast(bf16x8,
            *reinterpret_cast<const u16x8*>(bp + nt * 16 * LDP + kb * 32));
        acc[nt] = __builtin_amdgcn_mfma_f32_16x16x32_bf16(a, b, acc[nt], 0, 0, 0);
      }
    }
  }

  // C/D layout: col = lane&15, row = (lane>>4)*4 + reg; epilogue: +bias, tanh
  const int rbase = m0 + w * 16 + kq * 4;
#pragma unroll
  for (int nt = 0; nt < 8; ++nt) {
    int col = nt * 16 + r0;
    float bb = bsum[col];
#pragma unroll
    for (int reg = 0; reg < 4; ++reg) {
      int gm = rbase + reg;
      if (gm < M) {
        float v = tanhf(acc[nt][reg] + bb);
        if (out_f32) {
          ((float*)outp)[(size_t)gm * F + col] = v;
        } else {
          ((unsigned short*)outp)[(size_t)gm * F + col] = f2bf(v);
        }
      }
    }
  }
}

extern "C" void kernel_launch(void* const* d_in, const int* in_sizes, int n_in,
                              void* d_out, int out_size, void* d_ws, size_t ws_size,
                              hipStream_t stream) {
  const float* emb = (const float*)d_in[0];
  const float* W1  = (const float*)d_in[1];
  const float* b1  = (const float*)d_in[2];
  const float* W2  = (const float*)d_in[3];
  const float* b2  = (const float*)d_in[4];
  const int* e_src = (const int*)d_in[5];
  const int* e_dst = (const int*)d_in[6];
  const int* qsrc  = (const int*)d_in[7];
  const int* qdst  = (const int*)d_in[8];
  float* out = (float*)d_out;

  char* p = (char*)d_ws;
  size_t off = 0;
  auto take = [&](size_t n) { void* q = p + off; off = (off + n + 255) & ~(size_t)255; return q; };
  int* cnt    = (int*)take(2ull * NREL * NN * 4 + 4);   // [out|in] counts + cursor tail
  int* cursor = cnt + 2 * NREL * NN;
  float* rs   = (float*)take(2ull * NREL * NN * 4);     // rsqrt of [out|in]
  int2* sc    = (int2*)take((size_t)NREL * NN * 8);     // {start, cnt} per bucket
  int* fill   = (int*)take((size_t)NREL * NN * 4);
  int2* epay  = (int2*)take((size_t)NREL * NE * 8);     // {src, w}
  unsigned short* Wtb = (unsigned short*)take(2ull * NREL * F * F * 2);
  float* bsum = (float*)take(2ull * F * 4);
  unsigned short* Xb  = (unsigned short*)take((size_t)NN * F * 2);
  unsigned short* Z   = (unsigned short*)take((size_t)NREL * NN * F * 2);

  float* rs_out = rs;
  float* rs_in  = rs + (size_t)NREL * NN;
  int* cnt_in   = cnt + (size_t)NREL * NN;

  hipMemsetAsync(cnt, 0, 2ull * NREL * NN * 4 + 4, stream);
  cnt_kernel<<<(NREL * NE + 255) / 256, 256, 0, stream>>>(e_src, e_dst, cnt);
  rs_kernel<<<(2 * NREL * NN + 255) / 256, 256, 0, stream>>>(cnt, rs);
  bucket_kernel<<<(NREL * NN + 255) / 256, 256, 0, stream>>>(cnt_in, sc, fill, cursor);
  fill_kernel<<<(NREL * NE + 255) / 256, 256, 0, stream>>>(e_src, e_dst, sc, fill,
                                                           rs_out, rs_in, epay);
  wcvt_kernel<<<(2 * NREL * F * F + 255) / 256, 256, 0, stream>>>(W1, W2, Wtb);
  bias_kernel<<<1, 256, 0, stream>>>(b1, b2, bsum);
  cvtx_kernel<<<(NN * F / 8 + 255) / 256, 256, 0, stream>>>(emb, Xb);

  // layer 1: Z1 at all nodes, fused GEMM writes bf16 h1 back into Xb
  dim3 ag1((NN + 15) / 16, NREL);
  aggz_kernel<<<ag1, 256, 0, stream>>>(Xb, sc, epay, nullptr, nullptr, Z, NN);
  gemmf_kernel<<<(NN + BM - 1) / BM, 256, 0, stream>>>(Z, Wtb, bsum, Xb, NN, 0);

  // layer 2: only the 2*NQ query slots
  dim3 ag2((2 * NQ + 15) / 16, NREL);
  aggz_kernel<<<ag2, 256, 0, stream>>>(Xb, sc, epay, qsrc, qdst, Z, 2 * NQ);
  gemmf_kernel<<<(2 * NQ + BM - 1) / BM, 256, 0, stream>>>(
      Z, Wtb + (size_t)NREL * F * F, bsum + F, out, 2 * NQ, 1);
}

// Round 6
// 224.820 us; speedup vs baseline: 3.5284x; 1.2151x over previous
//
#include <hip/hip_runtime.h>
#include <stdint.h>

#define NN 100000   // nodes
#define NREL 3
#define NE 200000   // edges per relation
#define F 128       // feature dim (in = hid = out)
#define NQ 4096

#define NBUCK (NREL * NN)          // 300000 buckets
#define SCAN_PER_BLK 1024          // elements per scan block (256 thr x 4)
#define NSCANBLK ((NBUCK + SCAN_PER_BLK - 1) / SCAN_PER_BLK)  // 293
#define SCANB_PER 5                // ceil(293/64) elements per lane in scanB

typedef float fx4 __attribute__((ext_vector_type(4)));
typedef unsigned short u16x8 __attribute__((ext_vector_type(8)));
typedef __bf16 bf16x8 __attribute__((ext_vector_type(8)));

__device__ __forceinline__ unsigned short f2bf(float f) {
  uint32_t u = __builtin_bit_cast(uint32_t, f);
  uint32_t r = u + 0x7FFFu + ((u >> 16) & 1u);
  return (unsigned short)(r >> 16);
}
__device__ __forceinline__ float bf2f(unsigned short u) {
  return __builtin_bit_cast(float, (uint32_t)u << 16);
}

// ---- integer degree counts: cnt[0..3NN) = out-deg per rel, cnt[3NN..6NN) = in-deg ----
__global__ void cnt_kernel(const int* __restrict__ es, const int* __restrict__ ed,
                           int* __restrict__ cnt) {
  int i = blockIdx.x * blockDim.x + threadIdx.x;
  if (i >= NREL * NE) return;
  int r = i / NE;
  atomicAdd(&cnt[r * NN + es[i]], 1);
  atomicAdd(&cnt[NREL * NN + r * NN + ed[i]], 1);
}

// ---- deterministic hierarchical exclusive scan over cnt_in (no global atomics) ----
// A: per-block (1024 elems) totals
__global__ __launch_bounds__(256) void scanA_kernel(const int* __restrict__ cnt_in,
                                                    int* __restrict__ bsum) {
  int b = blockIdx.x, t = threadIdx.x;
  int base = b * SCAN_PER_BLK + t * 4;
  int s = 0;
#pragma unroll
  for (int k = 0; k < 4; ++k) {
    int i = base + k;
    if (i < NBUCK) s += cnt_in[i];
  }
#pragma unroll
  for (int d = 1; d < 64; d <<= 1) s += __shfl_xor(s, d);
  __shared__ int ws[4];
  if ((t & 63) == 0) ws[t >> 6] = s;
  __syncthreads();
  if (t == 0) bsum[b] = ws[0] + ws[1] + ws[2] + ws[3];
}

// B: exclusive scan of the NSCANBLK block totals (single wave)
__global__ void scanB_kernel(int* __restrict__ bsum) {
  int lane = threadIdx.x;  // 64 threads
  int v[SCANB_PER];
  int s = 0;
#pragma unroll
  for (int k = 0; k < SCANB_PER; ++k) {
    int i = lane * SCANB_PER + k;
    v[k] = (i < NSCANBLK) ? bsum[i] : 0;
    s += v[k];
  }
  int sc = s;
#pragma unroll
  for (int d = 1; d < 64; d <<= 1) {
    int o = __shfl_up(sc, d);
    if (lane >= d) sc += o;
  }
  int excl = sc - s;
#pragma unroll
  for (int k = 0; k < SCANB_PER; ++k) {
    int i = lane * SCANB_PER + k;
    if (i < NSCANBLK) { bsum[i] = excl; excl += v[k]; }
  }
}

// C: per-block rescan -> sc[i] = {start, cnt}, fill = 0
__global__ __launch_bounds__(256) void scanC_kernel(const int* __restrict__ cnt_in,
                                                    const int* __restrict__ bsum,
                                                    int2* __restrict__ scb,
                                                    int* __restrict__ fill) {
  int b = blockIdx.x, t = threadIdx.x;
  int base = b * SCAN_PER_BLK + t * 4;
  int c[4];
  int s = 0;
#pragma unroll
  for (int k = 0; k < 4; ++k) {
    int i = base + k;
    c[k] = (i < NBUCK) ? cnt_in[i] : 0;
    s += c[k];
  }
  int lane = t & 63, w = t >> 6;
  int sc = s;
#pragma unroll
  for (int d = 1; d < 64; d <<= 1) {
    int o = __shfl_up(sc, d);
    if (lane >= d) sc += o;
  }
  int thr_excl = sc - s;
  __shared__ int wtot[4];
  if (lane == 63) wtot[w] = sc;
  __syncthreads();
  int wave_off = 0;
#pragma unroll
  for (int ww = 0; ww < 3; ++ww) wave_off += (ww < w) ? wtot[ww] : 0;
  int start = bsum[b] + wave_off + thr_excl;
#pragma unroll
  for (int k = 0; k < 4; ++k) {
    int i = base + k;
    if (i < NBUCK) {
      scb[i] = make_int2(start, c[k]);
      fill[i] = 0;
      start += c[k];
    }
  }
}

// place each edge into its dst bucket; payload = {src, w = rsqrt(outdeg)*rsqrt(indeg)}
// (both degrees >= 1 for a real edge, so the clip is a no-op)
__global__ void fill_kernel(const int* __restrict__ es, const int* __restrict__ ed,
                            const int* __restrict__ cnt,
                            const int2* __restrict__ scb, int* __restrict__ fill,
                            int2* __restrict__ epay) {
  int i = blockIdx.x * blockDim.x + threadIdx.x;
  if (i >= NREL * NE) return;
  int r = i / NE;
  int s = es[i], d = ed[i];
  int b = r * NN + d;
  int2 m = scb[b];
  int pos = m.x + atomicAdd(&fill[b], 1);
  int co = cnt[r * NN + s];
  float w = rsqrtf((float)co) * rsqrtf((float)m.y);
  epay[pos] = make_int2(s, __builtin_bit_cast(int, w));
}

// Wtb[layer][rel][n][k] = bf16(W[layer][rel][k][n])
__global__ void wcvt_kernel(const float* __restrict__ W1, const float* __restrict__ W2,
                            unsigned short* __restrict__ Wtb) {
  int i = blockIdx.x * blockDim.x + threadIdx.x;
  if (i >= 2 * NREL * F * F) return;
  int l = i / (NREL * F * F);
  int rem = i % (NREL * F * F);
  int r = rem / (F * F);
  int nk = rem % (F * F);
  int n = nk >> 7, k = nk & 127;
  const float* W = l ? W2 : W1;
  Wtb[i] = f2bf(W[r * F * F + k * F + n]);
}

// bsum[l][f] = sum_r b_l[r][f]
__global__ void bias_kernel(const float* __restrict__ b1, const float* __restrict__ b2,
                            float* __restrict__ bsum) {
  int t = threadIdx.x;  // 256
  int l = t >> 7, f = t & 127;
  const float* b = l ? b2 : b1;
  bsum[l * F + f] = b[f] + b[F + f] + b[2 * F + f];
}

// X (f32) -> Xb (bf16)
__global__ void cvtx_kernel(const float* __restrict__ x, unsigned short* __restrict__ xb) {
  int i = blockIdx.x * blockDim.x + threadIdx.x;  // one per 8 elems
  const float* p = x + (size_t)i * 8;
  unsigned short tmp[8];
#pragma unroll
  for (int e = 0; e < 8; ++e) tmp[e] = f2bf(p[e]);
  *reinterpret_cast<u16x8*>(xb + (size_t)i * 8) = *reinterpret_cast<u16x8*>(tmp);
}

// ---- aggregate-first: Z[r][m][f] = sum_{e in bucket(r,n)} w_e * X[src_e][f]
// 16 lanes per m-row (j = lane&15 -> features j*8..j*8+7), 4 rows per wave.
__global__ __launch_bounds__(256) void aggz_kernel(const unsigned short* __restrict__ X,
                                                   const int2* __restrict__ scb,
                                                   const int2* __restrict__ epay,
                                                   const int* __restrict__ qsrc,
                                                   const int* __restrict__ qdst,
                                                   unsigned short* __restrict__ Z, int M) {
  const int r = blockIdx.y;
  const int t = threadIdx.x;
  const int lane = t & 63;
  const int m = blockIdx.x * 16 + (t >> 6) * 4 + (lane >> 4);
  const int j = lane & 15;
  if (m >= M) return;
  int n = qsrc ? ((m < NQ) ? qsrc[m] : qdst[m - NQ]) : m;
  int2 meta = scb[r * NN + n];
  const int2* ep = epay + meta.x;
  const int c = meta.y;

  float ps[8];
#pragma unroll
  for (int k = 0; k < 8; ++k) ps[k] = 0.f;

  int i = 0;
  for (; i + 2 <= c; i += 2) {
    int2 p0 = ep[i], p1 = ep[i + 1];
    float w0 = __builtin_bit_cast(float, p0.y);
    float w1 = __builtin_bit_cast(float, p1.y);
    u16x8 v0 = *reinterpret_cast<const u16x8*>(X + ((size_t)p0.x << 7) + j * 8);
    u16x8 v1 = *reinterpret_cast<const u16x8*>(X + ((size_t)p1.x << 7) + j * 8);
#pragma unroll
    for (int k = 0; k < 8; ++k)
      ps[k] = fmaf(bf2f(v1[k]), w1, fmaf(bf2f(v0[k]), w0, ps[k]));
  }
  if (i < c) {
    int2 p0 = ep[i];
    float w0 = __builtin_bit_cast(float, p0.y);
    u16x8 v0 = *reinterpret_cast<const u16x8*>(X + ((size_t)p0.x << 7) + j * 8);
#pragma unroll
    for (int k = 0; k < 8; ++k) ps[k] = fmaf(bf2f(v0[k]), w0, ps[k]);
  }

  unsigned short tmp[8];
#pragma unroll
  for (int k = 0; k < 8; ++k) tmp[k] = f2bf(ps[k]);
  *reinterpret_cast<u16x8*>(Z + (((size_t)r * M + m) << 7) + j * 8) =
      *reinterpret_cast<u16x8*>(tmp);
}

// fused K=384 GEMM: out[m] = tanh( sum_r Z[r][m] @ W_r + bsum )
#define BM 64
#define LDP 136
__global__ __launch_bounds__(256) void gemmf_kernel(const unsigned short* __restrict__ Z,
                                                    const unsigned short* __restrict__ Wt3,
                                                    const float* __restrict__ bsum,
                                                    void* __restrict__ outp,
                                                    int M, int out_f32) {
  __shared__ unsigned short A_lds[BM * LDP];
  __shared__ unsigned short W_lds[F * LDP];
  const int t = threadIdx.x;
  const int m0 = blockIdx.x * BM;
  const int lane = t & 63, w = t >> 6;
  const int r0 = lane & 15, kq = lane >> 4;

  fx4 acc[8];
#pragma unroll
  for (int nt = 0; nt < 8; ++nt) acc[nt] = (fx4){0.f, 0.f, 0.f, 0.f};

  for (int r = 0; r < NREL; ++r) {
    __syncthreads();  // previous chunk's LDS reads done
    const unsigned short* Wt = Wt3 + (size_t)r * F * F;
#pragma unroll
    for (int i = 0; i < 8; ++i) {
      int c = t + i * 256;
      int n = c >> 4, kc = (c & 15) * 8;
      *reinterpret_cast<u16x8*>(&W_lds[n * LDP + kc]) =
          *reinterpret_cast<const u16x8*>(Wt + n * F + kc);
    }
#pragma unroll
    for (int i = 0; i < 4; ++i) {
      int c = t + i * 256;
      int row = c >> 4, cg = (c & 15) * 8;
      int gm = m0 + row;
      u16x8 v;
      if (gm < M) {
        v = *reinterpret_cast<const u16x8*>(Z + (((size_t)r * M + gm) << 7) + cg);
      } else {
        v = (u16x8)0;
      }
      *reinterpret_cast<u16x8*>(&A_lds[row * LDP + cg]) = v;
    }
    __syncthreads();

    const unsigned short* ap = &A_lds[(w * 16 + r0) * LDP + kq * 8];
    const unsigned short* bp = &W_lds[r0 * LDP + kq * 8];
#pragma unroll
    for (int kb = 0; kb < 4; ++kb) {
      bf16x8 a = __builtin_bit_cast(bf16x8, *reinterpret_cast<const u16x8*>(ap + kb * 32));
#pragma unroll
      for (int nt = 0; nt < 8; ++nt) {
        bf16x8 b = __builtin_bit_cast(bf16x8,
            *reinterpret_cast<const u16x8*>(bp + nt * 16 * LDP + kb * 32));
        acc[nt] = __builtin_amdgcn_mfma_f32_16x16x32_bf16(a, b, acc[nt], 0, 0, 0);
      }
    }
  }

  // C/D layout: col = lane&15, row = (lane>>4)*4 + reg; epilogue: +bias, tanh
  const int rbase = m0 + w * 16 + kq * 4;
#pragma unroll
  for (int nt = 0; nt < 8; ++nt) {
    int col = nt * 16 + r0;
    float bb = bsum[col];
#pragma unroll
    for (int reg = 0; reg < 4; ++reg) {
      int gm = rbase + reg;
      if (gm < M) {
        float v = tanhf(acc[nt][reg] + bb);
        if (out_f32) {
          ((float*)outp)[(size_t)gm * F + col] = v;
        } else {
          ((unsigned short*)outp)[(size_t)gm * F + col] = f2bf(v);
        }
      }
    }
  }
}

extern "C" void kernel_launch(void* const* d_in, const int* in_sizes, int n_in,
                              void* d_out, int out_size, void* d_ws, size_t ws_size,
                              hipStream_t stream) {
  const float* emb = (const float*)d_in[0];
  const float* W1  = (const float*)d_in[1];
  const float* b1  = (const float*)d_in[2];
  const float* W2  = (const float*)d_in[3];
  const float* b2  = (const float*)d_in[4];
  const int* e_src = (const int*)d_in[5];
  const int* e_dst = (const int*)d_in[6];
  const int* qsrc  = (const int*)d_in[7];
  const int* qdst  = (const int*)d_in[8];
  float* out = (float*)d_out;

  char* p = (char*)d_ws;
  size_t off = 0;
  auto take = [&](size_t n) { void* q = p + off; off = (off + n + 255) & ~(size_t)255; return q; };
  int* cnt    = (int*)take(2ull * NREL * NN * 4);       // [out|in] counts
  int* blksum = (int*)take((size_t)NSCANBLK * 4);       // scan block sums
  int2* scb   = (int2*)take((size_t)NBUCK * 8);         // {start, cnt} per bucket
  int* fill   = (int*)take((size_t)NBUCK * 4);
  int2* epay  = (int2*)take((size_t)NREL * NE * 8);     // {src, w}
  unsigned short* Wtb = (unsigned short*)take(2ull * NREL * F * F * 2);
  float* bsum = (float*)take(2ull * F * 4);
  unsigned short* Xb  = (unsigned short*)take((size_t)NN * F * 2);
  unsigned short* Z   = (unsigned short*)take((size_t)NREL * NN * F * 2);

  int* cnt_in = cnt + (size_t)NREL * NN;

  hipMemsetAsync(cnt, 0, 2ull * NREL * NN * 4, stream);
  cnt_kernel<<<(NREL * NE + 255) / 256, 256, 0, stream>>>(e_src, e_dst, cnt);
  scanA_kernel<<<NSCANBLK, 256, 0, stream>>>(cnt_in, blksum);
  scanB_kernel<<<1, 64, 0, stream>>>(blksum);
  scanC_kernel<<<NSCANBLK, 256, 0, stream>>>(cnt_in, blksum, scb, fill);
  fill_kernel<<<(NREL * NE + 255) / 256, 256, 0, stream>>>(e_src, e_dst, cnt, scb, fill, epay);
  wcvt_kernel<<<(2 * NREL * F * F + 255) / 256, 256, 0, stream>>>(W1, W2, Wtb);
  bias_kernel<<<1, 256, 0, stream>>>(b1, b2, bsum);
  cvtx_kernel<<<(NN * F / 8 + 255) / 256, 256, 0, stream>>>(emb, Xb);

  // layer 1: Z1 at all nodes, fused GEMM writes bf16 h1 back into Xb
  dim3 ag1((NN + 15) / 16, NREL);
  aggz_kernel<<<ag1, 256, 0, stream>>>(Xb, scb, epay, nullptr, nullptr, Z, NN);
  gemmf_kernel<<<(NN + BM - 1) / BM, 256, 0, stream>>>(Z, Wtb, bsum, Xb, NN, 0);

  // layer 2: only the 2*NQ query slots
  dim3 ag2((2 * NQ + 15) / 16, NREL);
  aggz_kernel<<<ag2, 256, 0, stream>>>(Xb, scb, epay, qsrc, qdst, Z, 2 * NQ);
  gemmf_kernel<<<(2 * NQ + BM - 1) / BM, 256, 0, stream>>>(
      Z, Wtb + (size_t)NREL * F * F, bsum + F, out, 2 * NQ, 1);
}

// Round 7
// 221.315 us; speedup vs baseline: 3.5843x; 1.0158x over previous
//
#include <hip/hip_runtime.h>
#include <stdint.h>

#define NN 100000   // nodes
#define NREL 3
#define NE 200000   // edges per relation
#define F 128       // feature dim (in = hid = out)
#define NQ 4096

#define NBUCK (NREL * NN)          // 300000 buckets
#define SCAN_PER_BLK 1024          // elements per scan block (256 thr x 4)
#define NSCANBLK ((NBUCK + SCAN_PER_BLK - 1) / SCAN_PER_BLK)  // 293
#define SCANB_PER 5                // ceil(293/64) elements per lane in scanB

typedef float fx4 __attribute__((ext_vector_type(4)));
typedef unsigned short u16x8 __attribute__((ext_vector_type(8)));
typedef __bf16 bf16x8 __attribute__((ext_vector_type(8)));

__device__ __forceinline__ unsigned short f2bf(float f) {
  uint32_t u = __builtin_bit_cast(uint32_t, f);
  uint32_t r = u + 0x7FFFu + ((u >> 16) & 1u);
  return (unsigned short)(r >> 16);
}
__device__ __forceinline__ float bf2f(unsigned short u) {
  return __builtin_bit_cast(float, (uint32_t)u << 16);
}

// ---- integer degree counts: cnt[0..3NN) = out-deg per rel, cnt[3NN..6NN) = in-deg ----
__global__ void cnt_kernel(const int* __restrict__ es, const int* __restrict__ ed,
                           int* __restrict__ cnt) {
  int i = blockIdx.x * blockDim.x + threadIdx.x;
  if (i >= NREL * NE) return;
  int r = i / NE;
  atomicAdd(&cnt[r * NN + es[i]], 1);
  atomicAdd(&cnt[NREL * NN + r * NN + ed[i]], 1);
}

// ---- deterministic hierarchical exclusive scan over cnt_in (no global atomics) ----
__global__ __launch_bounds__(256) void scanA_kernel(const int* __restrict__ cnt_in,
                                                    int* __restrict__ bsum) {
  int b = blockIdx.x, t = threadIdx.x;
  int base = b * SCAN_PER_BLK + t * 4;
  int s = 0;
#pragma unroll
  for (int k = 0; k < 4; ++k) {
    int i = base + k;
    if (i < NBUCK) s += cnt_in[i];
  }
#pragma unroll
  for (int d = 1; d < 64; d <<= 1) s += __shfl_xor(s, d);
  __shared__ int ws[4];
  if ((t & 63) == 0) ws[t >> 6] = s;
  __syncthreads();
  if (t == 0) bsum[b] = ws[0] + ws[1] + ws[2] + ws[3];
}

__global__ void scanB_kernel(int* __restrict__ bsum) {
  int lane = threadIdx.x;  // 64 threads
  int v[SCANB_PER];
  int s = 0;
#pragma unroll
  for (int k = 0; k < SCANB_PER; ++k) {
    int i = lane * SCANB_PER + k;
    v[k] = (i < NSCANBLK) ? bsum[i] : 0;
    s += v[k];
  }
  int sc = s;
#pragma unroll
  for (int d = 1; d < 64; d <<= 1) {
    int o = __shfl_up(sc, d);
    if (lane >= d) sc += o;
  }
  int excl = sc - s;
#pragma unroll
  for (int k = 0; k < SCANB_PER; ++k) {
    int i = lane * SCANB_PER + k;
    if (i < NSCANBLK) { bsum[i] = excl; excl += v[k]; }
  }
}

__global__ __launch_bounds__(256) void scanC_kernel(const int* __restrict__ cnt_in,
                                                    const int* __restrict__ bsum,
                                                    int2* __restrict__ scb,
                                                    int* __restrict__ fill) {
  int b = blockIdx.x, t = threadIdx.x;
  int base = b * SCAN_PER_BLK + t * 4;
  int c[4];
  int s = 0;
#pragma unroll
  for (int k = 0; k < 4; ++k) {
    int i = base + k;
    c[k] = (i < NBUCK) ? cnt_in[i] : 0;
    s += c[k];
  }
  int lane = t & 63, w = t >> 6;
  int sc = s;
#pragma unroll
  for (int d = 1; d < 64; d <<= 1) {
    int o = __shfl_up(sc, d);
    if (lane >= d) sc += o;
  }
  int thr_excl = sc - s;
  __shared__ int wtot[4];
  if (lane == 63) wtot[w] = sc;
  __syncthreads();
  int wave_off = 0;
#pragma unroll
  for (int ww = 0; ww < 3; ++ww) wave_off += (ww < w) ? wtot[ww] : 0;
  int start = bsum[b] + wave_off + thr_excl;
#pragma unroll
  for (int k = 0; k < 4; ++k) {
    int i = base + k;
    if (i < NBUCK) {
      scb[i] = make_int2(start, c[k]);
      fill[i] = 0;
      start += c[k];
    }
  }
}

// place each edge into its dst bucket; payload = {src, w = rsqrt(outdeg)*rsqrt(indeg)}
__global__ void fill_kernel(const int* __restrict__ es, const int* __restrict__ ed,
                            const int* __restrict__ cnt,
                            const int2* __restrict__ scb, int* __restrict__ fill,
                            int2* __restrict__ epay) {
  int i = blockIdx.x * blockDim.x + threadIdx.x;
  if (i >= NREL * NE) return;
  int r = i / NE;
  int s = es[i], d = ed[i];
  int b = r * NN + d;
  int2 m = scb[b];
  int pos = m.x + atomicAdd(&fill[b], 1);
  int co = cnt[r * NN + s];
  float w = rsqrtf((float)co) * rsqrtf((float)m.y);
  epay[pos] = make_int2(s, __builtin_bit_cast(int, w));
}

// Wtb[layer][rel][n][k] = bf16(W[layer][rel][k][n])
__global__ void wcvt_kernel(const float* __restrict__ W1, const float* __restrict__ W2,
                            unsigned short* __restrict__ Wtb) {
  int i = blockIdx.x * blockDim.x + threadIdx.x;
  if (i >= 2 * NREL * F * F) return;
  int l = i / (NREL * F * F);
  int rem = i % (NREL * F * F);
  int r = rem / (F * F);
  int nk = rem % (F * F);
  int n = nk >> 7, k = nk & 127;
  const float* W = l ? W2 : W1;
  Wtb[i] = f2bf(W[r * F * F + k * F + n]);
}

// bsum[l][f] = sum_r b_l[r][f]
__global__ void bias_kernel(const float* __restrict__ b1, const float* __restrict__ b2,
                            float* __restrict__ bsum) {
  int t = threadIdx.x;  // 256
  int l = t >> 7, f = t & 127;
  const float* b = l ? b2 : b1;
  bsum[l * F + f] = b[f] + b[F + f] + b[2 * F + f];
}

// X (f32) -> Xb (bf16)
__global__ void cvtx_kernel(const float* __restrict__ x, unsigned short* __restrict__ xb) {
  int i = blockIdx.x * blockDim.x + threadIdx.x;  // one per 8 elems
  const float* p = x + (size_t)i * 8;
  unsigned short tmp[8];
#pragma unroll
  for (int e = 0; e < 8; ++e) tmp[e] = f2bf(p[e]);
  *reinterpret_cast<u16x8*>(xb + (size_t)i * 8) = *reinterpret_cast<u16x8*>(tmp);
}

// ---- aggregate-first: Z[r][m][f] = sum_{e in bucket(r,n)} w_e * X[src_e][f]
// 16 lanes per m-row (j = lane&15 -> features j*8..j*8+7), 4 rows per wave.
__global__ __launch_bounds__(256) void aggz_kernel(const unsigned short* __restrict__ X,
                                                   const int2* __restrict__ scb,
                                                   const int2* __restrict__ epay,
                                                   const int* __restrict__ qsrc,
                                                   const int* __restrict__ qdst,
                                                   unsigned short* __restrict__ Z, int M) {
  const int r = blockIdx.y;
  const int t = threadIdx.x;
  const int lane = t & 63;
  const int m = blockIdx.x * 16 + (t >> 6) * 4 + (lane >> 4);
  const int j = lane & 15;
  if (m >= M) return;
  int n = qsrc ? ((m < NQ) ? qsrc[m] : qdst[m - NQ]) : m;
  int2 meta = scb[r * NN + n];
  const int2* ep = epay + meta.x;
  const int c = meta.y;

  float ps[8];
#pragma unroll
  for (int k = 0; k < 8; ++k) ps[k] = 0.f;

  int i = 0;
  for (; i + 2 <= c; i += 2) {
    int2 p0 = ep[i], p1 = ep[i + 1];
    float w0 = __builtin_bit_cast(float, p0.y);
    float w1 = __builtin_bit_cast(float, p1.y);
    u16x8 v0 = *reinterpret_cast<const u16x8*>(X + ((size_t)p0.x << 7) + j * 8);
    u16x8 v1 = *reinterpret_cast<const u16x8*>(X + ((size_t)p1.x << 7) + j * 8);
#pragma unroll
    for (int k = 0; k < 8; ++k)
      ps[k] = fmaf(bf2f(v1[k]), w1, fmaf(bf2f(v0[k]), w0, ps[k]));
  }
  if (i < c) {
    int2 p0 = ep[i];
    float w0 = __builtin_bit_cast(float, p0.y);
    u16x8 v0 = *reinterpret_cast<const u16x8*>(X + ((size_t)p0.x << 7) + j * 8);
#pragma unroll
    for (int k = 0; k < 8; ++k) ps[k] = fmaf(bf2f(v0[k]), w0, ps[k]);
  }

  unsigned short tmp[8];
#pragma unroll
  for (int k = 0; k < 8; ++k) tmp[k] = f2bf(ps[k]);
  *reinterpret_cast<u16x8*>(Z + (((size_t)r * M + m) << 7) + j * 8) =
      *reinterpret_cast<u16x8*>(tmp);
}

// ---- fused K=384 GEMM: out[m] = tanh( sum_r Z[r][m] @ W_r + bsum ) ----
// 512 thr (8 waves, 2m x 4n), BM=128, XOR-swizzled LDS (c ^= row&7, no pad),
// cross-chunk pipeline: chunk r+1 global loads issued before chunk r MFMA.
#define GBM 128
__global__ __launch_bounds__(512) void gemmf_kernel(const unsigned short* __restrict__ Z,
                                                    const unsigned short* __restrict__ Wt3,
                                                    const float* __restrict__ bsum,
                                                    void* __restrict__ outp,
                                                    int M, int out_f32) {
  __shared__ unsigned short A_lds[GBM * F];   // [row][c^ (row&7)] chunks of 8 elems
  __shared__ unsigned short W_lds[F * F];
  const int t = threadIdx.x;
  const int m0 = blockIdx.x * GBM;
  const int lane = t & 63, w = t >> 6;
  const int wm = w >> 2, wn = w & 3;          // 2m x 4n wave grid
  const int r0 = lane & 15, kq = lane >> 4;

  u16x8 areg[4], wreg[4];

  fx4 acc[4][2];
#pragma unroll
  for (int mt = 0; mt < 4; ++mt)
#pragma unroll
    for (int nt = 0; nt < 2; ++nt) acc[mt][nt] = (fx4){0.f, 0.f, 0.f, 0.f};

  // prologue: load chunk 0 into regs
#pragma unroll
  for (int i = 0; i < 4; ++i) {
    int slot = t + i * 512;
    int row = slot >> 4, c = slot & 15;
    int gm = m0 + row;
    areg[i] = (gm < M)
        ? *reinterpret_cast<const u16x8*>(Z + (((size_t)gm) << 7) + c * 8)
        : (u16x8)0;
    wreg[i] = *reinterpret_cast<const u16x8*>(Wt3 + row * F + c * 8);
  }

  for (int r = 0; r < NREL; ++r) {
    __syncthreads();  // prior chunk's LDS reads complete
#pragma unroll
    for (int i = 0; i < 4; ++i) {
      int slot = t + i * 512;
      int row = slot >> 4, cs = (slot & 15) ^ (row & 7);
      *reinterpret_cast<u16x8*>(&A_lds[row * F + cs * 8]) = areg[i];
      *reinterpret_cast<u16x8*>(&W_lds[row * F + cs * 8]) = wreg[i];
    }
    __syncthreads();

    // issue next chunk's global loads BEFORE the MFMA phase (latency hides under it)
    if (r + 1 < NREL) {
      const unsigned short* Wt = Wt3 + (size_t)(r + 1) * F * F;
#pragma unroll
      for (int i = 0; i < 4; ++i) {
        int slot = t + i * 512;
        int row = slot >> 4, c = slot & 15;
        int gm = m0 + row;
        areg[i] = (gm < M)
            ? *reinterpret_cast<const u16x8*>(Z + (((size_t)(r + 1) * M + gm) << 7) + c * 8)
            : (u16x8)0;
        wreg[i] = *reinterpret_cast<const u16x8*>(Wt + row * F + c * 8);
      }
    }

    // MFMA over this chunk: rows wm*64+mt*16+r0, cols wn*32+nt*16+r0
    // row ≡ r0 (mod 8) for both A and W reads -> shared swizzle term
#pragma unroll
    for (int kb = 0; kb < 4; ++kb) {
      const int cs = ((kb * 4 + kq) ^ (r0 & 7)) * 8;
      bf16x8 a[4], b[2];
#pragma unroll
      for (int mt = 0; mt < 4; ++mt) {
        int row = wm * 64 + mt * 16 + r0;
        a[mt] = __builtin_bit_cast(bf16x8,
            *reinterpret_cast<const u16x8*>(&A_lds[row * F + cs]));
      }
#pragma unroll
      for (int nt = 0; nt < 2; ++nt) {
        int row = wn * 32 + nt * 16 + r0;
        b[nt] = __builtin_bit_cast(bf16x8,
            *reinterpret_cast<const u16x8*>(&W_lds[row * F + cs]));
      }
#pragma unroll
      for (int mt = 0; mt < 4; ++mt)
#pragma unroll
        for (int nt = 0; nt < 2; ++nt)
          acc[mt][nt] = __builtin_amdgcn_mfma_f32_16x16x32_bf16(a[mt], b[nt], acc[mt][nt], 0, 0, 0);
    }
  }

  // epilogue: C/D layout col = lane&15, row = (lane>>4)*4 + reg; +bias, tanh
#pragma unroll
  for (int mt = 0; mt < 4; ++mt) {
    const int rbase = m0 + wm * 64 + mt * 16 + kq * 4;
#pragma unroll
    for (int nt = 0; nt < 2; ++nt) {
      int col = wn * 32 + nt * 16 + r0;
      float bb = bsum[col];
#pragma unroll
      for (int reg = 0; reg < 4; ++reg) {
        int gm = rbase + reg;
        if (gm < M) {
          float v = tanhf(acc[mt][nt][reg] + bb);
          if (out_f32) {
            ((float*)outp)[(size_t)gm * F + col] = v;
          } else {
            ((unsigned short*)outp)[(size_t)gm * F + col] = f2bf(v);
          }
        }
      }
    }
  }
}

extern "C" void kernel_launch(void* const* d_in, const int* in_sizes, int n_in,
                              void* d_out, int out_size, void* d_ws, size_t ws_size,
                              hipStream_t stream) {
  const float* emb = (const float*)d_in[0];
  const float* W1  = (const float*)d_in[1];
  const float* b1  = (const float*)d_in[2];
  const float* W2  = (const float*)d_in[3];
  const float* b2  = (const float*)d_in[4];
  const int* e_src = (const int*)d_in[5];
  const int* e_dst = (const int*)d_in[6];
  const int* qsrc  = (const int*)d_in[7];
  const int* qdst  = (const int*)d_in[8];
  float* out = (float*)d_out;

  char* p = (char*)d_ws;
  size_t off = 0;
  auto take = [&](size_t n) { void* q = p + off; off = (off + n + 255) & ~(size_t)255; return q; };
  int* cnt    = (int*)take(2ull * NREL * NN * 4);       // [out|in] counts
  int* blksum = (int*)take((size_t)NSCANBLK * 4);       // scan block sums
  int2* scb   = (int2*)take((size_t)NBUCK * 8);         // {start, cnt} per bucket
  int* fill   = (int*)take((size_t)NBUCK * 4);
  int2* epay  = (int2*)take((size_t)NREL * NE * 8);     // {src, w}
  unsigned short* Wtb = (unsigned short*)take(2ull * NREL * F * F * 2);
  float* bsum = (float*)take(2ull * F * 4);
  unsigned short* Xb  = (unsigned short*)take((size_t)NN * F * 2);
  unsigned short* Z   = (unsigned short*)take((size_t)NREL * NN * F * 2);

  int* cnt_in = cnt + (size_t)NREL * NN;

  hipMemsetAsync(cnt, 0, 2ull * NREL * NN * 4, stream);
  cnt_kernel<<<(NREL * NE + 255) / 256, 256, 0, stream>>>(e_src, e_dst, cnt);
  scanA_kernel<<<NSCANBLK, 256, 0, stream>>>(cnt_in, blksum);
  scanB_kernel<<<1, 64, 0, stream>>>(blksum);
  scanC_kernel<<<NSCANBLK, 256, 0, stream>>>(cnt_in, blksum, scb, fill);
  fill_kernel<<<(NREL * NE + 255) / 256, 256, 0, stream>>>(e_src, e_dst, cnt, scb, fill, epay);
  wcvt_kernel<<<(2 * NREL * F * F + 255) / 256, 256, 0, stream>>>(W1, W2, Wtb);
  bias_kernel<<<1, 256, 0, stream>>>(b1, b2, bsum);
  cvtx_kernel<<<(NN * F / 8 + 255) / 256, 256, 0, stream>>>(emb, Xb);

  // layer 1: Z1 at all nodes, fused GEMM writes bf16 h1 back into Xb
  dim3 ag1((NN + 15) / 16, NREL);
  aggz_kernel<<<ag1, 256, 0, stream>>>(Xb, scb, epay, nullptr, nullptr, Z, NN);
  gemmf_kernel<<<(NN + GBM - 1) / GBM, 512, 0, stream>>>(Z, Wtb, bsum, Xb, NN, 0);

  // layer 2: only the 2*NQ query slots
  dim3 ag2((2 * NQ + 15) / 16, NREL);
  aggz_kernel<<<ag2, 256, 0, stream>>>(Xb, scb, epay, qsrc, qdst, Z, 2 * NQ);
  gemmf_kernel<<<(2 * NQ + GBM - 1) / GBM, 512, 0, stream>>>(
      Z, Wtb + (size_t)NREL * F * F, bsum + F, out, 2 * NQ, 1);
}